// Round 17
// baseline (3760.975 us; speedup 1.0000x reference)
//
#include <hip/hip_runtime.h>
#include <math.h>

// Problem dims (fixed by reference)
#define BB 32
#define CC 8
#define TT 64
#define FF 256
#define HH 512
#define G3 1536
#define NSEQ 256            // BB*CC
#define MROWS 16384         // NSEQ*TT

#define SGRP 16             // sequence groups (16 seqs each)
#define NGRP 4              // N-split ways (384 preact cols each)

typedef _Float16 f16x8 __attribute__((ext_vector_type(8)));
typedef float f32x4 __attribute__((ext_vector_type(4)));

// ---------------- fallback fp32 input GEMM ----------------
#define TMg 128
#define TNg 128
#define TKg 16

__global__ __launch_bounds__(256) void gemm_bias(
    const float* __restrict__ A, const float* __restrict__ W,
    const float* __restrict__ bias, float* __restrict__ C,
    int M, int N, int K)
{
  __shared__ float As[TKg][TMg + 4];
  __shared__ float Ws[TKg][TNg + 4];
  const int bm = blockIdx.y * TMg;
  const int bn = blockIdx.x * TNg;
  const int tid = threadIdx.x;
  const int tx = tid & 15;
  const int ty = tid >> 4;
  float acc[8][8];
#pragma unroll
  for (int i = 0; i < 8; ++i)
#pragma unroll
    for (int j = 0; j < 8; ++j) acc[i][j] = 0.f;

  for (int k0 = 0; k0 < K; k0 += TKg) {
    __syncthreads();
#pragma unroll
    for (int i = 0; i < 8; ++i) {
      int e = i * 256 + tid;
      int r = e >> 4;
      int c = e & 15;
      As[c][r] = A[(size_t)(bm + r) * K + (k0 + c)];
      Ws[c][r] = W[(size_t)(bn + r) * K + (k0 + c)];
    }
    __syncthreads();
#pragma unroll
    for (int k = 0; k < TKg; ++k) {
      float a[8], w[8];
#pragma unroll
      for (int i = 0; i < 8; ++i) a[i] = As[k][ty * 8 + i];
#pragma unroll
      for (int j = 0; j < 8; ++j) w[j] = Ws[k][tx + 16 * j];
#pragma unroll
      for (int i = 0; i < 8; ++i)
#pragma unroll
        for (int j = 0; j < 8; ++j) acc[i][j] = fmaf(a[i], w[j], acc[i][j]);
    }
  }
#pragma unroll
  for (int i = 0; i < 8; ++i) {
    size_t m = (size_t)(bm + ty * 8 + i);
#pragma unroll
    for (int j = 0; j < 8; ++j) {
      int n = bn + tx + 16 * j;
      C[m * N + n] = acc[i][j] + bias[n];
    }
  }
}

// ---------------- fp32 -> fp16 convert (vectorized x8) ----------------
__global__ __launch_bounds__(256) void conv16(
    const float* __restrict__ x, _Float16* __restrict__ xh, int n8)
{
  int i = blockIdx.x * 256 + threadIdx.x;
  if (i < n8) {
    float4 a = reinterpret_cast<const float4*>(x)[i * 2];
    float4 b = reinterpret_cast<const float4*>(x)[i * 2 + 1];
    f16x8 v;
    v[0] = (_Float16)a.x; v[1] = (_Float16)a.y; v[2] = (_Float16)a.z; v[3] = (_Float16)a.w;
    v[4] = (_Float16)b.x; v[5] = (_Float16)b.y; v[6] = (_Float16)b.z; v[7] = (_Float16)b.w;
    reinterpret_cast<f16x8*>(xh)[i] = v;
  }
}

// ---------------- pack W[G3][K] fp32 -> fp16 B-fragments (for GEMM0) ----------------
__global__ __launch_bounds__(256) void pack_wih(
    const float* __restrict__ W, _Float16* __restrict__ P, int K)
{
  int id = blockIdx.x * 256 + threadIdx.x;
  int lane = id & 63;
  int kcs = K >> 5;
  int t6 = id >> 6;
  int kc = t6 % kcs;
  int tile = t6 / kcs;
  if (tile >= 96) return;
  int row = tile * 16 + (lane & 15);
  int k0 = kc * 32 + ((lane >> 4) * 8);
  const float* src = W + (size_t)row * K + k0;
  f16x8 v;
#pragma unroll
  for (int i = 0; i < 8; ++i) v[i] = (_Float16)src[i];
  *reinterpret_cast<f16x8*>(P + (size_t)id * 8) = v;
}

// ---------------- pack W[G3][512] -> fp16 B-fragments, 4-way N-split order ------
// P[ng(4)][tl(24)][kc(16)][lane(64)][8]; tl = gate*8 + sub; global tile = gate*32+ng*8+sub
__global__ __launch_bounds__(256) void pack_whh(
    const float* __restrict__ W, _Float16* __restrict__ P)
{
  int id = blockIdx.x * 256 + threadIdx.x;    // 0 .. 98303
  int lane = id & 63;
  int kc = (id >> 6) & 15;
  int tidx = id >> 10;                        // 0..95 = ng*24 + tl
  int ng = tidx / 24;
  int tl = tidx % 24;
  int g = tl >> 3, sub = tl & 7;
  int gt = g * 32 + ng * 8 + sub;
  int row = gt * 16 + (lane & 15);
  int k0 = kc * 32 + ((lane >> 4) * 8);
  const float* src = W + (size_t)row * HH + k0;
  f16x8 v;
#pragma unroll
  for (int i = 0; i < 8; ++i) v[i] = (_Float16)src[i];
  *reinterpret_cast<f16x8*>(P + (size_t)id * 8) = v;
}

// ---------------- MFMA input GEMM (r14-proven): C = A(fp16) @ Wpack^T + bias ----------
__device__ __forceinline__ void gload16g(const _Float16* g, _Float16* l) {
  __builtin_amdgcn_global_load_lds(
      (const __attribute__((address_space(1))) unsigned int*)g,
      (__attribute__((address_space(3))) unsigned int*)l, 16, 0, 0);
}

__global__ __launch_bounds__(256, 2) void gemm_mfma(
    const _Float16* __restrict__ A, const _Float16* __restrict__ Bp,
    const float* __restrict__ bias, float* __restrict__ C, int K)
{
  __shared__ __align__(16) _Float16 As[2][128][36];
  __shared__ __align__(16) _Float16 Bs[2][8 * 512];

  const int tid = threadIdx.x;
  const int lane = tid & 63;
  const int wv = tid >> 6;
  const int wm = wv >> 1, wn = wv & 1;
  const int bnT = blockIdx.x * 8;
  const int bm = blockIdx.y * 128;
  const int kcs = K >> 5;

  const int arow = lane & 15;
  const int agrp = lane >> 4;
  const int dcol = lane & 15;
  const int mrow = (lane >> 4) * 4;

  f32x4 acc[4][4];
#pragma unroll
  for (int i = 0; i < 4; ++i)
#pragma unroll
    for (int j = 0; j < 4; ++j) acc[i][j] = (f32x4){0.f, 0.f, 0.f, 0.f};

  auto stageA = [&](int s, int b) {
#pragma unroll
    for (int p = 0; p < 2; ++p) {
      int idx = p * 256 + tid;
      int row = idx >> 2;
      int cs = idx & 3;
      f16x8 v = *reinterpret_cast<const f16x8*>(
          A + (size_t)(bm + row) * K + s * 32 + cs * 8);
      *reinterpret_cast<f16x8*>(&As[b][row][cs * 8]) = v;
    }
  };
  auto stageB = [&](int s, int b) {
#pragma unroll
    for (int q = 0; q < 2; ++q) {
      int nt = wv * 2 + q;
      const _Float16* src = Bp + ((size_t)((bnT + nt) * kcs + s) * 64 + lane) * 8;
      gload16g(src, &Bs[b][nt * 512]);
    }
  };

  stageA(0, 0);
  stageB(0, 0);
  __syncthreads();

  for (int s = 0; s < kcs; ++s) {
    const int b = s & 1;
    if (s + 1 < kcs) {
      stageA(s + 1, b ^ 1);
      stageB(s + 1, b ^ 1);
    }
    f16x8 af[4], bf[4];
#pragma unroll
    for (int mt = 0; mt < 4; ++mt)
      af[mt] = *reinterpret_cast<const f16x8*>(&As[b][wm * 64 + mt * 16 + arow][agrp * 8]);
#pragma unroll
    for (int nt = 0; nt < 4; ++nt)
      bf[nt] = *reinterpret_cast<const f16x8*>(&Bs[b][(wn * 4 + nt) * 512 + lane * 8]);
#pragma unroll
    for (int mt = 0; mt < 4; ++mt)
#pragma unroll
      for (int nt = 0; nt < 4; ++nt)
        acc[mt][nt] = __builtin_amdgcn_mfma_f32_16x16x32_f16(af[mt], bf[nt], acc[mt][nt], 0, 0, 0);
    __syncthreads();
  }

#pragma unroll
  for (int nt = 0; nt < 4; ++nt) {
    const int n = (bnT + wn * 4 + nt) * 16 + dcol;
    const float bv = bias[n];
#pragma unroll
    for (int mt = 0; mt < 4; ++mt) {
      const size_t m0 = (size_t)(bm + wm * 64 + mt * 16 + mrow);
#pragma unroll
      for (int r = 0; r < 4; ++r)
        C[(m0 + r) * G3 + n] = acc[mt][nt][r] + bv;
    }
  }
}

// ---------------- fused 2-stage pipelined two-layer scan ----------------
// 128 blocks (cooperative): [0,64)=scan0, [64,128)=scan1+folded-GEMM1.
// Stage shape = r14-proven (512 thr, sg=b>>2, ng=b&3, LOADW/MF16 chains,
// fence -> fetch_add -> tid-poll protocol; absmax=0/6e-5 across r8/r14).
// scan1 computes gi1 IN REGISTERS: 3 chains A=h0(t) x pWih1 + 3 chains
// A=h1(t-1) x pWhh1 (no ring, no stage G — r15's failure sources removed).
// DAG: S0(t): f0[t-1], f1[t-2] | S1(t): f0[t], f1[t-1]. Acyclic, lag 1.
#define SPB2 16
#define HSTR 520

#define LOADW(P, buf, g)                                                         \
  {                                                                              \
    const _Float16* _s = (P) +                                                   \
        (((size_t)(ng * 24 + (g) * 8 + wid)) * 16) * 512 + (size_t)lane * 8;     \
    _Pragma("unroll")                                                            \
    for (int kc = 0; kc < 16; ++kc)                                              \
      buf[kc] = *reinterpret_cast<const f16x8*>(_s + (size_t)kc * 512);          \
  }

#define MF16H(H, buf, acc)                                                       \
  {                                                                              \
    _Pragma("unroll")                                                            \
    for (int kc = 0; kc < 16; ++kc) {                                            \
      f16x8 _ha = *reinterpret_cast<const f16x8*>(&(H)[arow][kc * 32 + agrp * 8]); \
      acc = __builtin_amdgcn_mfma_f32_16x16x32_f16(_ha, buf[kc], acc, 0, 0, 0);  \
    }                                                                            \
  }

#define PUBLISH(F)                                                               \
  __threadfence();                                                               \
  __syncthreads();                                                               \
  if (tid == 0)                                                                  \
    __hip_atomic_fetch_add(&(F)[sg * TT + t], 1u,                                \
                           __ATOMIC_RELEASE, __HIP_MEMORY_SCOPE_AGENT);

#define POLL(F, tt)                                                              \
  while (__hip_atomic_load(&(F)[sg * TT + (tt)],                                 \
                           __ATOMIC_ACQUIRE, __HIP_MEMORY_SCOPE_AGENT) < NGRP) {}

#define HCOPY(H, SRC, par)                                                       \
  {                                                                              \
    const _Float16* _src = (SRC) + (size_t)(par) * NSEQ * HH                     \
                           + (size_t)seq0 * HH + (size_t)tid * 16;               \
    int _e0 = tid * 16, _row = _e0 >> 9, _col = _e0 & 511;                       \
    *reinterpret_cast<f16x8*>(&(H)[_row][_col])     = *reinterpret_cast<const f16x8*>(_src); \
    *reinterpret_cast<f16x8*>(&(H)[_row][_col + 8]) = *reinterpret_cast<const f16x8*>(_src + 8); \
  }

__global__ __launch_bounds__(512, 1) void gru_fused2(
    const float* __restrict__ gi0,     // [NSEQ][TT][G3] from GEMM0
    const _Float16* __restrict__ pWhh0,
    const _Float16* __restrict__ pWih1,
    const _Float16* __restrict__ pWhh1,
    const float* __restrict__ bhh0,
    const float* __restrict__ bih1,
    const float* __restrict__ bhh1,
    float* __restrict__ hfin,          // [NSEQ][HH]
    _Float16* __restrict__ hx0,        // [2][NSEQ][HH]
    _Float16* __restrict__ hx1,        // [2][NSEQ][HH]
    unsigned int* __restrict__ f0,     // [SGRP][TT] (zeroed)
    unsigned int* __restrict__ f1)     // [SGRP][TT] (zeroed)
{
  __shared__ __align__(16) _Float16 hs0[SPB2][HSTR];   // 16.6 KB
  __shared__ __align__(16) _Float16 hs1[SPB2][HSTR];   // 16.6 KB (scan1 only)

  const int tid = threadIdx.x;
  const int lane = tid & 63;
  const int wid = tid >> 6;                   // 0..7
  const int role = blockIdx.x >> 6;           // 0=scan0, 1=scan1
  const int b = blockIdx.x & 63;
  const int sg = b >> 2;
  const int ng = b & 3;                       // constant per XCD (bid%8 -> ng=k&3)
  const int seq0 = sg * SPB2;

  const int arow = lane & 15;
  const int agrp = lane >> 4;
  const int dcol = lane & 15;
  const int mrow = (lane >> 4) * 4;
  const int cg = ng * 128 + wid * 16 + dcol;

  for (int e = tid; e < SPB2 * HSTR; e += 512) {
    hs0[e / HSTR][e % HSTR] = (_Float16)0.f;
    hs1[e / HSTR][e % HSTR] = (_Float16)0.f;
  }
  __syncthreads();

  if (role == 0) {
    // ================= stage 0: layer-0 scan (r14-proven) =================
    const float bhr = bhh0[cg], bhz = bhh0[HH + cg], bhn = bhh0[2 * HH + cg];
    float hold[4] = {0.f, 0.f, 0.f, 0.f};

    for (int t = 0; t < TT; ++t) {
      float gir[4], giz[4], gin[4];
#pragma unroll
      for (int r = 0; r < 4; ++r) {
        const float* p0 = gi0 + ((size_t)(seq0 + mrow + r) * TT + t) * G3;
        gir[r] = p0[cg]; giz[r] = p0[HH + cg]; gin[r] = p0[2 * HH + cg];
      }

      if (t > 0) {
        if (tid == 0) POLL(f0, t - 1)
        if (t > 1 && tid == 1) POLL(f1, t - 2)     // hx0 parity WAR backpressure
        __syncthreads();
        HCOPY(hs0, hx0, t & 1)                     // h0(t-1)
        __syncthreads();
      }

      f16x8 bufA[16], bufB[16];
      f32x4 aR = {0.f,0.f,0.f,0.f}, aZ = {0.f,0.f,0.f,0.f}, aN = {0.f,0.f,0.f,0.f};
      LOADW(pWhh0, bufA, 0)
      LOADW(pWhh0, bufB, 1)
      MF16H(hs0, bufA, aR)
      LOADW(pWhh0, bufA, 2)
      MF16H(hs0, bufB, aZ)
      MF16H(hs0, bufA, aN)

      const int nb = (t + 1) & 1;
#pragma unroll
      for (int r = 0; r < 4; ++r) {
        float hr = aR[r] + bhr, hz = aZ[r] + bhz, hn = aN[r] + bhn;
        float rr = __builtin_amdgcn_rcpf(1.f + __expf(-(gir[r] + hr)));
        float zz = __builtin_amdgcn_rcpf(1.f + __expf(-(giz[r] + hz)));
        float ex = __expf(2.f * (gin[r] + rr * hn));
        float nn = 1.f - 2.f * __builtin_amdgcn_rcpf(ex + 1.f);
        float hnew = nn + zz * (hold[r] - nn);
        hold[r] = hnew;
        hx0[(size_t)nb * NSEQ * HH + (size_t)(seq0 + mrow + r) * HH + cg] = (_Float16)hnew;
      }
      PUBLISH(f0)
    }
  } else {
    // ========== stage 1: layer-1 scan with folded gi1 GEMM ==========
    const float bir = bih1[cg], biz = bih1[HH + cg], bin = bih1[2 * HH + cg];
    const float bhr = bhh1[cg], bhz = bhh1[HH + cg], bhn = bhh1[2 * HH + cg];
    float hold[4] = {0.f, 0.f, 0.f, 0.f};

    for (int t = 0; t < TT; ++t) {
      if (tid == 0) POLL(f0, t)                    // h0(t) ready
      if (t > 0 && tid == 1) POLL(f1, t - 1)       // own exchange of h1(t-1)
      __syncthreads();
      HCOPY(hs0, hx0, (t + 1) & 1)                 // h0(t)
      if (t > 0) HCOPY(hs1, hx1, t & 1)            // h1(t-1)
      __syncthreads();

      f16x8 bufA[16], bufB[16];
      f32x4 a0R = {0.f,0.f,0.f,0.f}, a0Z = {0.f,0.f,0.f,0.f}, a0N = {0.f,0.f,0.f,0.f};
      f32x4 a1R = {0.f,0.f,0.f,0.f}, a1Z = {0.f,0.f,0.f,0.f}, a1N = {0.f,0.f,0.f,0.f};
      LOADW(pWih1, bufA, 0)
      LOADW(pWih1, bufB, 1)
      MF16H(hs0, bufA, a0R)
      LOADW(pWih1, bufA, 2)
      MF16H(hs0, bufB, a0Z)
      LOADW(pWhh1, bufB, 0)
      MF16H(hs0, bufA, a0N)
      LOADW(pWhh1, bufA, 1)
      MF16H(hs1, bufB, a1R)
      LOADW(pWhh1, bufB, 2)
      MF16H(hs1, bufA, a1Z)
      MF16H(hs1, bufB, a1N)

      const int nb = (t + 1) & 1;
#pragma unroll
      for (int r = 0; r < 4; ++r) {
        float gir = a0R[r] + bir;                  // gi1 r-part (incl. bih1)
        float giz = a0Z[r] + biz;
        float gin = a0N[r] + bin;
        float hr = a1R[r] + bhr, hz = a1Z[r] + bhz, hn = a1N[r] + bhn;
        float rr = __builtin_amdgcn_rcpf(1.f + __expf(-(gir + hr)));
        float zz = __builtin_amdgcn_rcpf(1.f + __expf(-(giz + hz)));
        float ex = __expf(2.f * (gin + rr * hn));
        float nn = 1.f - 2.f * __builtin_amdgcn_rcpf(ex + 1.f);
        float hnew = nn + zz * (hold[r] - nn);
        hold[r] = hnew;
        hx1[(size_t)nb * NSEQ * HH + (size_t)(seq0 + mrow + r) * HH + cg] = (_Float16)hnew;
      }
      PUBLISH(f1)
    }

#pragma unroll
    for (int r = 0; r < 4; ++r)
      hfin[(size_t)(seq0 + mrow + r) * HH + cg] = hold[r];
  }
}

// ---------------- fallback fp32 scan (row-streaming) ----------------
#define QS 4
#define SCTH 512
__global__ __launch_bounds__(SCTH) void gru_scan2f(
    const float* __restrict__ gi, const float* __restrict__ W,
    const float* __restrict__ bhh, float* __restrict__ hfin,
    float* __restrict__ yout)
{
  __shared__ __align__(16) float hsl[HH][QS];
  const int col = threadIdx.x;
  const int seq0 = blockIdx.x * QS;
  const float bh0 = bhh[col];
  const float bh1 = bhh[HH + col];
  const float bh2 = bhh[2 * HH + col];
  const float* w0p = W + (size_t)col * HH;
  const float* w1p = W + (size_t)(HH + col) * HH;
  const float* w2p = W + (size_t)(2 * HH + col) * HH;

  *reinterpret_cast<float4*>(&hsl[col][0]) = make_float4(0.f, 0.f, 0.f, 0.f);
  __syncthreads();

  for (int t = 0; t < TT; ++t) {
    float acc0[QS], acc1[QS], acc2[QS];
#pragma unroll
    for (int s = 0; s < QS; ++s) { acc0[s] = bh0; acc1[s] = bh1; acc2[s] = bh2; }
    float4 ho = *reinterpret_cast<const float4*>(&hsl[col][0]);
    float hold[QS] = {ho.x, ho.y, ho.z, ho.w};
#pragma unroll 2
    for (int k0 = 0; k0 < HH; k0 += 4) {
      float w[3][4];
      float4 a = *reinterpret_cast<const float4*>(&w0p[k0]);
      w[0][0] = a.x; w[0][1] = a.y; w[0][2] = a.z; w[0][3] = a.w;
      float4 b = *reinterpret_cast<const float4*>(&w1p[k0]);
      w[1][0] = b.x; w[1][1] = b.y; w[1][2] = b.z; w[1][3] = b.w;
      float4 c = *reinterpret_cast<const float4*>(&w2p[k0]);
      w[2][0] = c.x; w[2][1] = c.y; w[2][2] = c.z; w[2][3] = c.w;
#pragma unroll
      for (int kk = 0; kk < 4; ++kk) {
        float4 h4 = *reinterpret_cast<const float4*>(&hsl[k0 + kk][0]);
        float hq[4] = {h4.x, h4.y, h4.z, h4.w};
#pragma unroll
        for (int s = 0; s < QS; ++s) {
          acc0[s] = fmaf(hq[s], w[0][kk], acc0[s]);
          acc1[s] = fmaf(hq[s], w[1][kk], acc1[s]);
          acc2[s] = fmaf(hq[s], w[2][kk], acc2[s]);
        }
      }
    }
    __syncthreads();
    float hnew[QS];
#pragma unroll
    for (int s = 0; s < QS; ++s) {
      size_t grow = ((size_t)(seq0 + s) * TT + t) * G3;
      float ir = gi[grow + col];
      float iz = gi[grow + HH + col];
      float inn = gi[grow + 2 * HH + col];
      float r = 1.f / (1.f + expf(-(ir + acc0[s])));
      float z = 1.f / (1.f + expf(-(iz + acc1[s])));
      float nn = tanhf(inn + r * acc2[s]);
      hnew[s] = (1.f - z) * nn + z * hold[s];
      if (yout) yout[((size_t)(seq0 + s) * TT + t) * HH + col] = hnew[s];
    }
    *reinterpret_cast<float4*>(&hsl[col][0]) =
        make_float4(hnew[0], hnew[1], hnew[2], hnew[3]);
    __syncthreads();
  }
#pragma unroll
  for (int s = 0; s < QS; ++s)
    hfin[(size_t)(seq0 + s) * HH + col] = hsl[col][s];
}

// ---------------- final FC + channel mean ----------------
__global__ __launch_bounds__(256) void fc_mean(
    const float* __restrict__ hfin, const float* __restrict__ fcW,
    const float* __restrict__ fcb, float* __restrict__ out)
{
  __shared__ float red[256];
  const int b = blockIdx.x;
  const int tid = threadIdx.x;
  float sum = 0.f;
  for (int e = tid; e < CC * HH; e += 256) {
    int c = e >> 9;
    int k = e & (HH - 1);
    sum += hfin[(size_t)(b * CC + c) * HH + k] * fcW[k];
  }
  red[tid] = sum;
  __syncthreads();
  for (int w = 128; w > 0; w >>= 1) {
    if (tid < w) red[tid] += red[tid + w];
    __syncthreads();
  }
  if (tid == 0) out[b] = red[0] * (1.f / CC) + fcb[0];
}

extern "C" void kernel_launch(void* const* d_in, const int* in_sizes, int n_in,
                              void* d_out, int out_size, void* d_ws, size_t ws_size,
                              hipStream_t stream)
{
  const float* x    = (const float*)d_in[0];
  const float* Wih0 = (const float*)d_in[1];
  const float* Whh0 = (const float*)d_in[2];
  const float* bih0 = (const float*)d_in[3];
  const float* bhh0 = (const float*)d_in[4];
  const float* Wih1 = (const float*)d_in[5];
  const float* Whh1 = (const float*)d_in[6];
  const float* bih1 = (const float*)d_in[7];
  const float* bhh1 = (const float*)d_in[8];
  const float* fcW  = (const float*)d_in[9];
  const float* fcb  = (const float*)d_in[10];
  float* out = (float*)d_out;

  // ws layout (fast path):
  //   gi0   [MROWS][G3] fp32  100,663,296 @ 0
  //   xh    [MROWS][FF] fp16    8,388,608 @ 100,663,296
  //   pWih0 fp16 (K=256)          786,432 @ 109,051,904
  //   pWhh0 fp16                1,572,864 @ 109,838,336
  //   pWih1 fp16                1,572,864 @ 111,411,200
  //   pWhh1 fp16                1,572,864 @ 112,984,064
  //   hx0   [2][NSEQ][HH] f16     524,288 @ 114,556,928
  //   hx1   [2][NSEQ][HH] f16     524,288 @ 115,081,216
  //   f0/f1 u32[16][64] x2          8,192 @ 115,605,504
  //   hfin  [NSEQ][HH] fp32       524,288 @ 115,613,696  (end 116,137,984)
  char* ws = (char*)d_ws;
  float* gibuf = (float*)ws;
  _Float16* xh    = (_Float16*)(ws + 100663296ull);
  _Float16* pWih0 = (_Float16*)(ws + 109051904ull);
  _Float16* pWhh0 = (_Float16*)(ws + 109838336ull);
  _Float16* pWih1 = (_Float16*)(ws + 111411200ull);
  _Float16* pWhh1 = (_Float16*)(ws + 112984064ull);
  _Float16* hx0   = (_Float16*)(ws + 114556928ull);
  _Float16* hx1   = (_Float16*)(ws + 115081216ull);
  unsigned int* f0 = (unsigned int*)(ws + 115605504ull);
  unsigned int* f1 = f0 + SGRP * TT;
  float* hfin = (float*)(ws + 115613696ull);
  // fallback layout: y0f fp32 @ 100,663,296, hfin @ 134,217,728
  float* y0f   = (float*)(ws + 100663296ull);
  float* hfinF = (float*)(ws + 134217728ull);
  const bool mfma_ok = (ws_size >= 134742016ull);

  if (mfma_ok) {
    // GEMM0: gi0 = x @ Wih0^T + bih0 (fp16 MFMA)
    conv16<<<dim3((MROWS * FF / 8 + 255) / 256), 256, 0, stream>>>(x, xh, MROWS * FF / 8);
    pack_wih<<<dim3(192), 256, 0, stream>>>(Wih0, pWih0, FF);
    gemm_mfma<<<dim3(12, 128), 256, 0, stream>>>(xh, pWih0, bih0, gibuf, FF);

    // packs for the fused pipeline
    pack_whh<<<dim3(384), 256, 0, stream>>>(Whh0, pWhh0);
    pack_whh<<<dim3(384), 256, 0, stream>>>(Wih1, pWih1);
    pack_whh<<<dim3(384), 256, 0, stream>>>(Whh1, pWhh1);
    hipMemsetAsync(f0, 0, 2 * SGRP * TT * sizeof(unsigned int), stream);

    // fused 2-stage pipelined two-layer scan (128 blocks, cooperative)
    {
      const float* a0 = gibuf; const _Float16* p0 = pWhh0; const _Float16* p1 = pWih1;
      const _Float16* p2 = pWhh1; const float* b0 = bhh0; const float* b1 = bih1;
      const float* b2 = bhh1; float* hf = hfin; _Float16* h0 = hx0; _Float16* h1 = hx1;
      unsigned int* F0 = f0; unsigned int* F1 = f1;
      void* args[] = {(void*)&a0, (void*)&p0, (void*)&p1, (void*)&p2, (void*)&b0,
                      (void*)&b1, (void*)&b2, (void*)&hf, (void*)&h0, (void*)&h1,
                      (void*)&F0, (void*)&F1};
      hipLaunchCooperativeKernel((const void*)gru_fused2, dim3(128), dim3(512),
                                 args, 0, stream);
    }

    fc_mean<<<dim3(BB), 256, 0, stream>>>(hfin, fcW, fcb, out);
  } else {
    gemm_bias<<<dim3(G3 / TNg, MROWS / TMg), 256, 0, stream>>>(x, Wih0, bih0, gibuf, MROWS, G3, FF);
    gru_scan2f<<<dim3(NSEQ / QS), SCTH, 0, stream>>>(gibuf, Whh0, bhh0, hfinF, y0f);
    gemm_bias<<<dim3(G3 / TNg, MROWS / TMg), 256, 0, stream>>>(y0f, Wih1, bih1, gibuf, MROWS, G3, HH);
    gru_scan2f<<<dim3(NSEQ / QS), SCTH, 0, stream>>>(gibuf, Whh1, bhh1, hfinF, nullptr);
    fc_mean<<<dim3(BB), 256, 0, stream>>>(hfinF, fcW, fcb, out);
  }
}

// Round 18
// 2157.728 us; speedup vs baseline: 1.7430x; 1.7430x over previous
//
#include <hip/hip_runtime.h>
#include <math.h>

// Problem dims (fixed by reference)
#define BB 32
#define CC 8
#define TT 64
#define FF 256
#define HH 512
#define G3 1536
#define NSEQ 256            // BB*CC
#define MROWS 16384         // NSEQ*TT

#define SGRP 16             // sequence groups (16 seqs each)
#define NGRP 4              // N-split ways (384 preact cols each)

typedef _Float16 f16x8 __attribute__((ext_vector_type(8)));
typedef float f32x4 __attribute__((ext_vector_type(4)));

// ---------------- fallback fp32 input GEMM ----------------
#define TMg 128
#define TNg 128
#define TKg 16

__global__ __launch_bounds__(256) void gemm_bias(
    const float* __restrict__ A, const float* __restrict__ W,
    const float* __restrict__ bias, float* __restrict__ C,
    int M, int N, int K)
{
  __shared__ float As[TKg][TMg + 4];
  __shared__ float Ws[TKg][TNg + 4];
  const int bm = blockIdx.y * TMg;
  const int bn = blockIdx.x * TNg;
  const int tid = threadIdx.x;
  const int tx = tid & 15;
  const int ty = tid >> 4;
  float acc[8][8];
#pragma unroll
  for (int i = 0; i < 8; ++i)
#pragma unroll
    for (int j = 0; j < 8; ++j) acc[i][j] = 0.f;

  for (int k0 = 0; k0 < K; k0 += TKg) {
    __syncthreads();
#pragma unroll
    for (int i = 0; i < 8; ++i) {
      int e = i * 256 + tid;
      int r = e >> 4;
      int c = e & 15;
      As[c][r] = A[(size_t)(bm + r) * K + (k0 + c)];
      Ws[c][r] = W[(size_t)(bn + r) * K + (k0 + c)];
    }
    __syncthreads();
#pragma unroll
    for (int k = 0; k < TKg; ++k) {
      float a[8], w[8];
#pragma unroll
      for (int i = 0; i < 8; ++i) a[i] = As[k][ty * 8 + i];
#pragma unroll
      for (int j = 0; j < 8; ++j) w[j] = Ws[k][tx + 16 * j];
#pragma unroll
      for (int i = 0; i < 8; ++i)
#pragma unroll
        for (int j = 0; j < 8; ++j) acc[i][j] = fmaf(a[i], w[j], acc[i][j]);
    }
  }
#pragma unroll
  for (int i = 0; i < 8; ++i) {
    size_t m = (size_t)(bm + ty * 8 + i);
#pragma unroll
    for (int j = 0; j < 8; ++j) {
      int n = bn + tx + 16 * j;
      C[m * N + n] = acc[i][j] + bias[n];
    }
  }
}

// ---------------- fp32 -> fp16 convert (vectorized x8) ----------------
__global__ __launch_bounds__(256) void conv16(
    const float* __restrict__ x, _Float16* __restrict__ xh, int n8)
{
  int i = blockIdx.x * 256 + threadIdx.x;
  if (i < n8) {
    float4 a = reinterpret_cast<const float4*>(x)[i * 2];
    float4 b = reinterpret_cast<const float4*>(x)[i * 2 + 1];
    f16x8 v;
    v[0] = (_Float16)a.x; v[1] = (_Float16)a.y; v[2] = (_Float16)a.z; v[3] = (_Float16)a.w;
    v[4] = (_Float16)b.x; v[5] = (_Float16)b.y; v[6] = (_Float16)b.z; v[7] = (_Float16)b.w;
    reinterpret_cast<f16x8*>(xh)[i] = v;
  }
}

// ---------------- pack W[G3][K] fp32 -> fp16 B-fragments ----------------
// P[tile(96)][kc(K/32)][lane(64)][8]; B-frag: n=lane&15 (W row in tile), k=kc*32+(lane>>4)*8+i
__global__ __launch_bounds__(256) void pack_wih(
    const float* __restrict__ W, _Float16* __restrict__ P, int K)
{
  int id = blockIdx.x * 256 + threadIdx.x;
  int lane = id & 63;
  int kcs = K >> 5;
  int t6 = id >> 6;
  int kc = t6 % kcs;
  int tile = t6 / kcs;
  if (tile >= 96) return;
  int row = tile * 16 + (lane & 15);
  int k0 = kc * 32 + ((lane >> 4) * 8);
  const float* src = W + (size_t)row * K + k0;
  f16x8 v;
#pragma unroll
  for (int i = 0; i < 8; ++i) v[i] = (_Float16)src[i];
  *reinterpret_cast<f16x8*>(P + (size_t)id * 8) = v;
}

// ---------------- pack Whh[G3][HH] -> fp16 B-fragments, 4-way N-split order ------
// P[ng(4)][tl(24)][kc(16)][lane(64)][8]; tl = gate*8 + sub; global tile = gate*32+ng*8+sub
__global__ __launch_bounds__(256) void pack_whh(
    const float* __restrict__ W, _Float16* __restrict__ P)
{
  int id = blockIdx.x * 256 + threadIdx.x;    // 0 .. 98303
  int lane = id & 63;
  int kc = (id >> 6) & 15;
  int tidx = id >> 10;                        // 0..95 = ng*24 + tl
  int ng = tidx / 24;
  int tl = tidx % 24;
  int g = tl >> 3, sub = tl & 7;
  int gt = g * 32 + ng * 8 + sub;
  int row = gt * 16 + (lane & 15);
  int k0 = kc * 32 + ((lane >> 4) * 8);
  const float* src = W + (size_t)row * HH + k0;
  f16x8 v;
#pragma unroll
  for (int i = 0; i < 8; ++i) v[i] = (_Float16)src[i];
  *reinterpret_cast<f16x8*>(P + (size_t)id * 8) = v;
}

// ---------------- MFMA input GEMM: C[M][G3] = A[M][K](fp16) @ Wpack^T + bias ----------
// 128x128 tile, BK=32, 256 threads = 4 waves (2x2). A via reg->padded LDS; B via
// global_load_lds (fragment-ordered pack). Double-buffered, 1 barrier per K-step.
__device__ __forceinline__ void gload16g(const _Float16* g, _Float16* l) {
  __builtin_amdgcn_global_load_lds(
      (const __attribute__((address_space(1))) unsigned int*)g,
      (__attribute__((address_space(3))) unsigned int*)l, 16, 0, 0);
}

__global__ __launch_bounds__(256, 2) void gemm_mfma(
    const _Float16* __restrict__ A,   // [MROWS][K] fp16
    const _Float16* __restrict__ Bp,  // packed [96][K/32][64][8]
    const float* __restrict__ bias,   // [G3]
    float* __restrict__ C,            // [MROWS][G3]
    int K)
{
  __shared__ __align__(16) _Float16 As[2][128][36];   // 18.4 KB padded
  __shared__ __align__(16) _Float16 Bs[2][8 * 512];   // 16 KB (frag order)

  const int tid = threadIdx.x;
  const int lane = tid & 63;
  const int wv = tid >> 6;
  const int wm = wv >> 1, wn = wv & 1;
  const int bnT = blockIdx.x * 8;             // first of 8 n-tiles
  const int bm = blockIdx.y * 128;
  const int kcs = K >> 5;

  const int arow = lane & 15;
  const int agrp = lane >> 4;
  const int dcol = lane & 15;
  const int mrow = (lane >> 4) * 4;

  f32x4 acc[4][4];
#pragma unroll
  for (int i = 0; i < 4; ++i)
#pragma unroll
    for (int j = 0; j < 4; ++j) acc[i][j] = (f32x4){0.f, 0.f, 0.f, 0.f};

  auto stageA = [&](int s, int b) {
#pragma unroll
    for (int p = 0; p < 2; ++p) {
      int idx = p * 256 + tid;
      int row = idx >> 2;
      int cs = idx & 3;
      f16x8 v = *reinterpret_cast<const f16x8*>(
          A + (size_t)(bm + row) * K + s * 32 + cs * 8);
      *reinterpret_cast<f16x8*>(&As[b][row][cs * 8]) = v;
    }
  };
  auto stageB = [&](int s, int b) {
#pragma unroll
    for (int q = 0; q < 2; ++q) {
      int nt = wv * 2 + q;
      const _Float16* src = Bp + ((size_t)((bnT + nt) * kcs + s) * 64 + lane) * 8;
      gload16g(src, &Bs[b][nt * 512]);
    }
  };

  stageA(0, 0);
  stageB(0, 0);
  __syncthreads();

  for (int s = 0; s < kcs; ++s) {
    const int b = s & 1;
    if (s + 1 < kcs) {
      stageA(s + 1, b ^ 1);
      stageB(s + 1, b ^ 1);
    }
    f16x8 af[4], bf[4];
#pragma unroll
    for (int mt = 0; mt < 4; ++mt)
      af[mt] = *reinterpret_cast<const f16x8*>(&As[b][wm * 64 + mt * 16 + arow][agrp * 8]);
#pragma unroll
    for (int nt = 0; nt < 4; ++nt)
      bf[nt] = *reinterpret_cast<const f16x8*>(&Bs[b][(wn * 4 + nt) * 512 + lane * 8]);
#pragma unroll
    for (int mt = 0; mt < 4; ++mt)
#pragma unroll
      for (int nt = 0; nt < 4; ++nt)
        acc[mt][nt] = __builtin_amdgcn_mfma_f32_16x16x32_f16(af[mt], bf[nt], acc[mt][nt], 0, 0, 0);
    __syncthreads();
  }

  // ---- epilogue: bias + store ----
#pragma unroll
  for (int nt = 0; nt < 4; ++nt) {
    const int n = (bnT + wn * 4 + nt) * 16 + dcol;
    const float bv = bias[n];
#pragma unroll
    for (int mt = 0; mt < 4; ++mt) {
      const size_t m0 = (size_t)(bm + wm * 64 + mt * 16 + mrow);
#pragma unroll
      for (int r = 0; r < 4; ++r)
        C[(m0 + r) * G3 + n] = acc[mt][nt][r] + bv;
    }
  }
}

// ---------------- MFMA recurrent scan (r8-proven, verbatim; yout fp16) ----------
#define SPB2 16
#define HSTR 520

#define LOADW(buf, g)                                                            \
  {                                                                              \
    const _Float16* _s = packW +                                                 \
        (((size_t)(ng * 24 + (g) * 8 + wid)) * 16) * 512 + (size_t)lane * 8;     \
    _Pragma("unroll")                                                            \
    for (int kc = 0; kc < 16; ++kc)                                              \
      buf[kc] = *reinterpret_cast<const f16x8*>(_s + (size_t)kc * 512);          \
  }

#define MF16(buf, acc)                                                           \
  {                                                                              \
    _Pragma("unroll")                                                            \
    for (int kc = 0; kc < 16; ++kc) {                                            \
      f16x8 _ha = *reinterpret_cast<const f16x8*>(&hs[arow][kc * 32 + agrp * 8]); \
      acc = __builtin_amdgcn_mfma_f32_16x16x32_f16(_ha, buf[kc], acc, 0, 0, 0);  \
    }                                                                            \
  }

__global__ __launch_bounds__(512, 2) void gru_scan_mfma(
    const float* __restrict__ gi,      // [NSEQ][TT][G3]
    const _Float16* __restrict__ packW,
    const float* __restrict__ bhh,     // [G3]
    float* __restrict__ hfin,          // [NSEQ][HH]
    _Float16* __restrict__ yout,       // [NSEQ][TT][HH] fp16 or nullptr
    _Float16* __restrict__ hx,         // [2][NSEQ][HH] exchange buffer
    unsigned int* __restrict__ flags)  // [SGRP][TT], zeroed pre-launch
{
  __shared__ __align__(16) _Float16 hs[SPB2][HSTR];   // 16.6 KB

  const int tid = threadIdx.x;
  const int lane = tid & 63;
  const int wid = tid >> 6;                   // 0..7
  const int bid = blockIdx.x;
  const int sg = bid >> 2;                    // seq group
  const int ng = bid & 3;                     // N group (uniform per XCD: 8 % 4 == 0)
  const int seq0 = sg * SPB2;

  const int arow = lane & 15;
  const int agrp = lane >> 4;
  const int dcol = lane & 15;
  const int mrow = (lane >> 4) * 4;

  const int cg = ng * 128 + wid * 16 + dcol;

  const float bhr = bhh[cg];
  const float bhz = bhh[HH + cg];
  const float bhn = bhh[2 * HH + cg];

  float hold[4] = {0.f, 0.f, 0.f, 0.f};

  for (int e = tid; e < SPB2 * HSTR; e += 512)
    hs[e / HSTR][e % HSTR] = (_Float16)0.f;
  __syncthreads();

  for (int t = 0; t < TT; ++t) {
    if (t > 0) {
      if (tid == 0) {
        while (__hip_atomic_load(&flags[sg * TT + (t - 1)],
                                 __ATOMIC_ACQUIRE, __HIP_MEMORY_SCOPE_AGENT) < NGRP) {}
      }
      __syncthreads();
      {
        const _Float16* src = hx + (size_t)(t & 1) * NSEQ * HH
                              + (size_t)seq0 * HH + (size_t)tid * 16;
        int e0 = tid * 16;
        int row = e0 >> 9;
        int col = e0 & 511;
        *reinterpret_cast<f16x8*>(&hs[row][col])     = *reinterpret_cast<const f16x8*>(src);
        *reinterpret_cast<f16x8*>(&hs[row][col + 8]) = *reinterpret_cast<const f16x8*>(src + 8);
      }
      __syncthreads();
    }

    float gir[4], giz[4], gin[4];
#pragma unroll
    for (int r = 0; r < 4; ++r) {
      const float* p0 = gi + ((size_t)(seq0 + mrow + r) * TT + t) * G3;
      gir[r] = p0[cg];
      giz[r] = p0[HH + cg];
      gin[r] = p0[2 * HH + cg];
    }

    f16x8 bufA[16], bufB[16];
    f32x4 aR = {0.f,0.f,0.f,0.f}, aZ = {0.f,0.f,0.f,0.f}, aN = {0.f,0.f,0.f,0.f};
    LOADW(bufA, 0)
    LOADW(bufB, 1)
    MF16(bufA, aR)
    LOADW(bufA, 2)
    MF16(bufB, aZ)
    MF16(bufA, aN)

    const int nb = (t + 1) & 1;
#pragma unroll
    for (int r = 0; r < 4; ++r) {
      float hr = aR[r] + bhr;
      float hz = aZ[r] + bhz;
      float hn = aN[r] + bhn;
      float rr = __builtin_amdgcn_rcpf(1.f + __expf(-(gir[r] + hr)));
      float zz = __builtin_amdgcn_rcpf(1.f + __expf(-(giz[r] + hz)));
      float ex = __expf(2.f * (gin[r] + rr * hn));
      float nn = 1.f - 2.f * __builtin_amdgcn_rcpf(ex + 1.f);
      float hnew = nn + zz * (hold[r] - nn);
      hold[r] = hnew;
      hx[(size_t)nb * NSEQ * HH + (size_t)(seq0 + mrow + r) * HH + cg] = (_Float16)hnew;
      if (yout)
        yout[((size_t)(seq0 + mrow + r) * TT + t) * HH + cg] = (_Float16)hnew;
    }

    __threadfence();
    __syncthreads();
    if (tid == 0)
      __hip_atomic_fetch_add(&flags[sg * TT + t], 1u,
                             __ATOMIC_RELEASE, __HIP_MEMORY_SCOPE_AGENT);
  }

#pragma unroll
  for (int r = 0; r < 4; ++r)
    hfin[(size_t)(seq0 + mrow + r) * HH + cg] = hold[r];
}

// ---------------- fallback fp32 scan (row-streaming) ----------------
#define QS 4
#define SCTH 512
__global__ __launch_bounds__(SCTH) void gru_scan2f(
    const float* __restrict__ gi, const float* __restrict__ W,
    const float* __restrict__ bhh, float* __restrict__ hfin,
    float* __restrict__ yout)
{
  __shared__ __align__(16) float hsl[HH][QS];
  const int col = threadIdx.x;
  const int seq0 = blockIdx.x * QS;
  const float bh0 = bhh[col];
  const float bh1 = bhh[HH + col];
  const float bh2 = bhh[2 * HH + col];
  const float* w0p = W + (size_t)col * HH;
  const float* w1p = W + (size_t)(HH + col) * HH;
  const float* w2p = W + (size_t)(2 * HH + col) * HH;

  *reinterpret_cast<float4*>(&hsl[col][0]) = make_float4(0.f, 0.f, 0.f, 0.f);
  __syncthreads();

  for (int t = 0; t < TT; ++t) {
    float acc0[QS], acc1[QS], acc2[QS];
#pragma unroll
    for (int s = 0; s < QS; ++s) { acc0[s] = bh0; acc1[s] = bh1; acc2[s] = bh2; }
    float4 ho = *reinterpret_cast<const float4*>(&hsl[col][0]);
    float hold[QS] = {ho.x, ho.y, ho.z, ho.w};
#pragma unroll 2
    for (int k0 = 0; k0 < HH; k0 += 4) {
      float w[3][4];
      float4 a = *reinterpret_cast<const float4*>(&w0p[k0]);
      w[0][0] = a.x; w[0][1] = a.y; w[0][2] = a.z; w[0][3] = a.w;
      float4 b = *reinterpret_cast<const float4*>(&w1p[k0]);
      w[1][0] = b.x; w[1][1] = b.y; w[1][2] = b.z; w[1][3] = b.w;
      float4 c = *reinterpret_cast<const float4*>(&w2p[k0]);
      w[2][0] = c.x; w[2][1] = c.y; w[2][2] = c.z; w[2][3] = c.w;
#pragma unroll
      for (int kk = 0; kk < 4; ++kk) {
        float4 h4 = *reinterpret_cast<const float4*>(&hsl[k0 + kk][0]);
        float hq[4] = {h4.x, h4.y, h4.z, h4.w};
#pragma unroll
        for (int s = 0; s < QS; ++s) {
          acc0[s] = fmaf(hq[s], w[0][kk], acc0[s]);
          acc1[s] = fmaf(hq[s], w[1][kk], acc1[s]);
          acc2[s] = fmaf(hq[s], w[2][kk], acc2[s]);
        }
      }
    }
    __syncthreads();
    float hnew[QS];
#pragma unroll
    for (int s = 0; s < QS; ++s) {
      size_t grow = ((size_t)(seq0 + s) * TT + t) * G3;
      float ir = gi[grow + col];
      float iz = gi[grow + HH + col];
      float inn = gi[grow + 2 * HH + col];
      float r = 1.f / (1.f + expf(-(ir + acc0[s])));
      float z = 1.f / (1.f + expf(-(iz + acc1[s])));
      float nn = tanhf(inn + r * acc2[s]);
      hnew[s] = (1.f - z) * nn + z * hold[s];
      if (yout) yout[((size_t)(seq0 + s) * TT + t) * HH + col] = hnew[s];
    }
    *reinterpret_cast<float4*>(&hsl[col][0]) =
        make_float4(hnew[0], hnew[1], hnew[2], hnew[3]);
    __syncthreads();
  }
#pragma unroll
  for (int s = 0; s < QS; ++s)
    hfin[(size_t)(seq0 + s) * HH + col] = hsl[col][s];
}

// ---------------- final FC + channel mean ----------------
__global__ __launch_bounds__(256) void fc_mean(
    const float* __restrict__ hfin, const float* __restrict__ fcW,
    const float* __restrict__ fcb, float* __restrict__ out)
{
  __shared__ float red[256];
  const int b = blockIdx.x;
  const int tid = threadIdx.x;
  float sum = 0.f;
  for (int e = tid; e < CC * HH; e += 256) {
    int c = e >> 9;
    int k = e & (HH - 1);
    sum += hfin[(size_t)(b * CC + c) * HH + k] * fcW[k];
  }
  red[tid] = sum;
  __syncthreads();
  for (int w = 128; w > 0; w >>= 1) {
    if (tid < w) red[tid] += red[tid + w];
    __syncthreads();
  }
  if (tid == 0) out[b] = red[0] * (1.f / CC) + fcb[0];
}

extern "C" void kernel_launch(void* const* d_in, const int* in_sizes, int n_in,
                              void* d_out, int out_size, void* d_ws, size_t ws_size,
                              hipStream_t stream)
{
  const float* x    = (const float*)d_in[0];
  const float* Wih0 = (const float*)d_in[1];
  const float* Whh0 = (const float*)d_in[2];
  const float* bih0 = (const float*)d_in[3];
  const float* bhh0 = (const float*)d_in[4];
  const float* Wih1 = (const float*)d_in[5];
  const float* Whh1 = (const float*)d_in[6];
  const float* bih1 = (const float*)d_in[7];
  const float* bhh1 = (const float*)d_in[8];
  const float* fcW  = (const float*)d_in[9];
  const float* fcb  = (const float*)d_in[10];
  float* out = (float*)d_out;

  // ws layout (fast path):
  //   gi    [MROWS][G3] fp32  100,663,296 @ 0
  //   y0h   [MROWS][HH] fp16   16,777,216 @ 100,663,296
  //   xh    [MROWS][FF] fp16    8,388,608 @ 117,440,512
  //   pWih  fp16 (K<=512)       1,572,864 @ 125,829,120
  //   pWhh  fp16                1,572,864 @ 127,401,984
  //   hx    [2][NSEQ][HH] fp16    524,288 @ 128,974,848
  //   flags [SGRP][NGRP][TT]       16,384 @ 129,499,136
  //   hfin  [NSEQ][HH] fp32       524,288 @ 134,217,728  (shared w/ fallback layout)
  char* ws = (char*)d_ws;
  float* gibuf = (float*)ws;
  _Float16* y0h  = (_Float16*)(ws + 100663296ull);
  _Float16* xh   = (_Float16*)(ws + 117440512ull);
  _Float16* pWih = (_Float16*)(ws + 125829120ull);
  _Float16* pWhh = (_Float16*)(ws + 127401984ull);
  _Float16* hx   = (_Float16*)(ws + 128974848ull);
  unsigned int* flags = (unsigned int*)(ws + 129499136ull);
  float* hfin = (float*)(ws + 134217728ull);
  float* y0f  = (float*)(ws + 100663296ull);   // fallback fp32 y0 (33.5 MB)
  const bool mfma_ok = (ws_size >= 134742016ull);

  if (mfma_ok) {
    // layer 0: x->fp16, pack Wih0, MFMA GEMM (K=256)
    conv16<<<dim3((MROWS * FF / 8 + 255) / 256), 256, 0, stream>>>(x, xh, MROWS * FF / 8);
    pack_wih<<<dim3(192), 256, 0, stream>>>(Wih0, pWih, FF);
    gemm_mfma<<<dim3(12, 128), 256, 0, stream>>>(xh, pWih, bih0, gibuf, FF);

    // layer 0 scan
    pack_whh<<<dim3(384), 256, 0, stream>>>(Whh0, pWhh);
    hipMemsetAsync(flags, 0, SGRP * NGRP * TT * sizeof(unsigned int), stream);
    gru_scan_mfma<<<dim3(SGRP * NGRP), 512, 0, stream>>>(gibuf, pWhh, bhh0, hfin, y0h, hx, flags);

    // layer 1: pack Wih1, MFMA GEMM (K=512) on fp16 y0
    pack_wih<<<dim3(384), 256, 0, stream>>>(Wih1, pWih, HH);
    gemm_mfma<<<dim3(12, 128), 256, 0, stream>>>(y0h, pWih, bih1, gibuf, HH);

    // layer 1 scan
    pack_whh<<<dim3(384), 256, 0, stream>>>(Whh1, pWhh);
    hipMemsetAsync(flags, 0, SGRP * NGRP * TT * sizeof(unsigned int), stream);
    gru_scan_mfma<<<dim3(SGRP * NGRP), 512, 0, stream>>>(gibuf, pWhh, bhh1, hfin, nullptr, hx, flags);
  } else {
    gemm_bias<<<dim3(G3 / TNg, MROWS / TMg), 256, 0, stream>>>(x, Wih0, bih0, gibuf, MROWS, G3, FF);
    gru_scan2f<<<dim3(NSEQ / QS), SCTH, 0, stream>>>(gibuf, Whh0, bhh0, hfin, y0f);
    gemm_bias<<<dim3(G3 / TNg, MROWS / TMg), 256, 0, stream>>>(y0f, Wih1, bih1, gibuf, MROWS, G3, HH);
    gru_scan2f<<<dim3(NSEQ / QS), SCTH, 0, stream>>>(gibuf, Whh1, bhh1, hfin, nullptr);
  }

  fc_mean<<<dim3(BB), 256, 0, stream>>>(hfin, fcW, fcb, out);
}

// Round 19
// 947.506 us; speedup vs baseline: 3.9693x; 2.2773x over previous
//
#include <hip/hip_runtime.h>
#include <math.h>

// Problem dims (fixed by reference)
#define BB 32
#define CC 8
#define TT 64
#define FF 256
#define HH 512
#define G3 1536
#define NSEQ 256            // BB*CC
#define MROWS 16384         // NSEQ*TT

#define SGRP 16             // sequence groups (16 seqs each)
#define NGRP 4              // N-split ways (384 preact cols each)

typedef _Float16 f16x8 __attribute__((ext_vector_type(8)));
typedef float f32x4 __attribute__((ext_vector_type(4)));

// ---------------- fallback fp32 input GEMM ----------------
#define TMg 128
#define TNg 128
#define TKg 16

__global__ __launch_bounds__(256) void gemm_bias(
    const float* __restrict__ A, const float* __restrict__ W,
    const float* __restrict__ bias, float* __restrict__ C,
    int M, int N, int K)
{
  __shared__ float As[TKg][TMg + 4];
  __shared__ float Ws[TKg][TNg + 4];
  const int bm = blockIdx.y * TMg;
  const int bn = blockIdx.x * TNg;
  const int tid = threadIdx.x;
  const int tx = tid & 15;
  const int ty = tid >> 4;
  float acc[8][8];
#pragma unroll
  for (int i = 0; i < 8; ++i)
#pragma unroll
    for (int j = 0; j < 8; ++j) acc[i][j] = 0.f;

  for (int k0 = 0; k0 < K; k0 += TKg) {
    __syncthreads();
#pragma unroll
    for (int i = 0; i < 8; ++i) {
      int e = i * 256 + tid;
      int r = e >> 4;
      int c = e & 15;
      As[c][r] = A[(size_t)(bm + r) * K + (k0 + c)];
      Ws[c][r] = W[(size_t)(bn + r) * K + (k0 + c)];
    }
    __syncthreads();
#pragma unroll
    for (int k = 0; k < TKg; ++k) {
      float a[8], w[8];
#pragma unroll
      for (int i = 0; i < 8; ++i) a[i] = As[k][ty * 8 + i];
#pragma unroll
      for (int j = 0; j < 8; ++j) w[j] = Ws[k][tx + 16 * j];
#pragma unroll
      for (int i = 0; i < 8; ++i)
#pragma unroll
        for (int j = 0; j < 8; ++j) acc[i][j] = fmaf(a[i], w[j], acc[i][j]);
    }
  }
#pragma unroll
  for (int i = 0; i < 8; ++i) {
    size_t m = (size_t)(bm + ty * 8 + i);
#pragma unroll
    for (int j = 0; j < 8; ++j) {
      int n = bn + tx + 16 * j;
      C[m * N + n] = acc[i][j] + bias[n];
    }
  }
}

// ---------------- fp32 -> fp16 convert (vectorized x8) ----------------
__global__ __launch_bounds__(256) void conv16(
    const float* __restrict__ x, _Float16* __restrict__ xh, int n8)
{
  int i = blockIdx.x * 256 + threadIdx.x;
  if (i < n8) {
    float4 a = reinterpret_cast<const float4*>(x)[i * 2];
    float4 b = reinterpret_cast<const float4*>(x)[i * 2 + 1];
    f16x8 v;
    v[0] = (_Float16)a.x; v[1] = (_Float16)a.y; v[2] = (_Float16)a.z; v[3] = (_Float16)a.w;
    v[4] = (_Float16)b.x; v[5] = (_Float16)b.y; v[6] = (_Float16)b.z; v[7] = (_Float16)b.w;
    reinterpret_cast<f16x8*>(xh)[i] = v;
  }
}

// ---------------- pack W[G3][K] fp32 -> fp16 B-fragments ----------------
// P[tile(96)][kc(K/32)][lane(64)][8]; B-frag: n=lane&15 (W row in tile), k=kc*32+(lane>>4)*8+i
__global__ __launch_bounds__(256) void pack_wih(
    const float* __restrict__ W, _Float16* __restrict__ P, int K)
{
  int id = blockIdx.x * 256 + threadIdx.x;
  int lane = id & 63;
  int kcs = K >> 5;
  int t6 = id >> 6;
  int kc = t6 % kcs;
  int tile = t6 / kcs;
  if (tile >= 96) return;
  int row = tile * 16 + (lane & 15);
  int k0 = kc * 32 + ((lane >> 4) * 8);
  const float* src = W + (size_t)row * K + k0;
  f16x8 v;
#pragma unroll
  for (int i = 0; i < 8; ++i) v[i] = (_Float16)src[i];
  *reinterpret_cast<f16x8*>(P + (size_t)id * 8) = v;
}

// ---------------- pack Whh[G3][HH] -> fp16 B-fragments, 4-way N-split order ------
// P[ng(4)][tl(24)][kc(16)][lane(64)][8]; tl = gate*8 + sub; global tile = gate*32+ng*8+sub
__global__ __launch_bounds__(256) void pack_whh(
    const float* __restrict__ W, _Float16* __restrict__ P)
{
  int id = blockIdx.x * 256 + threadIdx.x;    // 0 .. 98303
  int lane = id & 63;
  int kc = (id >> 6) & 15;
  int tidx = id >> 10;                        // 0..95 = ng*24 + tl
  int ng = tidx / 24;
  int tl = tidx % 24;
  int g = tl >> 3, sub = tl & 7;
  int gt = g * 32 + ng * 8 + sub;
  int row = gt * 16 + (lane & 15);
  int k0 = kc * 32 + ((lane >> 4) * 8);
  const float* src = W + (size_t)row * HH + k0;
  f16x8 v;
#pragma unroll
  for (int i = 0; i < 8; ++i) v[i] = (_Float16)src[i];
  *reinterpret_cast<f16x8*>(P + (size_t)id * 8) = v;
}

// ---------------- MFMA input GEMM (r14-proven): C = A(fp16) @ Wpack^T + bias ----------
__device__ __forceinline__ void gload16g(const _Float16* g, _Float16* l) {
  __builtin_amdgcn_global_load_lds(
      (const __attribute__((address_space(1))) unsigned int*)g,
      (__attribute__((address_space(3))) unsigned int*)l, 16, 0, 0);
}

__global__ __launch_bounds__(256, 2) void gemm_mfma(
    const _Float16* __restrict__ A,   // [MROWS][K] fp16
    const _Float16* __restrict__ Bp,  // packed [96][K/32][64][8]
    const float* __restrict__ bias,   // [G3]
    float* __restrict__ C,            // [MROWS][G3]
    int K)
{
  __shared__ __align__(16) _Float16 As[2][128][36];   // 18.4 KB padded
  __shared__ __align__(16) _Float16 Bs[2][8 * 512];   // 16 KB (frag order)

  const int tid = threadIdx.x;
  const int lane = tid & 63;
  const int wv = tid >> 6;
  const int wm = wv >> 1, wn = wv & 1;
  const int bnT = blockIdx.x * 8;             // first of 8 n-tiles
  const int bm = blockIdx.y * 128;
  const int kcs = K >> 5;

  const int arow = lane & 15;
  const int agrp = lane >> 4;
  const int dcol = lane & 15;
  const int mrow = (lane >> 4) * 4;

  f32x4 acc[4][4];
#pragma unroll
  for (int i = 0; i < 4; ++i)
#pragma unroll
    for (int j = 0; j < 4; ++j) acc[i][j] = (f32x4){0.f, 0.f, 0.f, 0.f};

  auto stageA = [&](int s, int b) {
#pragma unroll
    for (int p = 0; p < 2; ++p) {
      int idx = p * 256 + tid;
      int row = idx >> 2;
      int cs = idx & 3;
      f16x8 v = *reinterpret_cast<const f16x8*>(
          A + (size_t)(bm + row) * K + s * 32 + cs * 8);
      *reinterpret_cast<f16x8*>(&As[b][row][cs * 8]) = v;
    }
  };
  auto stageB = [&](int s, int b) {
#pragma unroll
    for (int q = 0; q < 2; ++q) {
      int nt = wv * 2 + q;
      const _Float16* src = Bp + ((size_t)((bnT + nt) * kcs + s) * 64 + lane) * 8;
      gload16g(src, &Bs[b][nt * 512]);
    }
  };

  stageA(0, 0);
  stageB(0, 0);
  __syncthreads();

  for (int s = 0; s < kcs; ++s) {
    const int b = s & 1;
    if (s + 1 < kcs) {
      stageA(s + 1, b ^ 1);
      stageB(s + 1, b ^ 1);
    }
    f16x8 af[4], bf[4];
#pragma unroll
    for (int mt = 0; mt < 4; ++mt)
      af[mt] = *reinterpret_cast<const f16x8*>(&As[b][wm * 64 + mt * 16 + arow][agrp * 8]);
#pragma unroll
    for (int nt = 0; nt < 4; ++nt)
      bf[nt] = *reinterpret_cast<const f16x8*>(&Bs[b][(wn * 4 + nt) * 512 + lane * 8]);
#pragma unroll
    for (int mt = 0; mt < 4; ++mt)
#pragma unroll
      for (int nt = 0; nt < 4; ++nt)
        acc[mt][nt] = __builtin_amdgcn_mfma_f32_16x16x32_f16(af[mt], bf[nt], acc[mt][nt], 0, 0, 0);
    __syncthreads();
  }

  // ---- epilogue: bias + store ----
#pragma unroll
  for (int nt = 0; nt < 4; ++nt) {
    const int n = (bnT + wn * 4 + nt) * 16 + dcol;
    const float bv = bias[n];
#pragma unroll
    for (int mt = 0; mt < 4; ++mt) {
      const size_t m0 = (size_t)(bm + wm * 64 + mt * 16 + mrow);
#pragma unroll
      for (int r = 0; r < 4; ++r)
        C[(m0 + r) * G3 + n] = acc[mt][nt][r] + bv;
    }
  }
}

// ---------------- MFMA recurrent scan: r14 structure + FENCELESS sc0/sc1 exchange ------
// 64 blocks = 16 sg x 4 ng (ng uniform per XCD under %8 dispatch -> one warm 384 KB
// weight slice per L2). NO acquire anywhere: hx consumer loads use sc0/sc1 scope bits
// (BYPASS L1/L2, read LLC directly — unlike r10's nt hint which could hit stale lines);
// hx producer stores are sc0/sc1 write-through; publish = vmcnt(0) drain -> barrier ->
// RELAXED per-producer flag; consumers: 4 relaxed poller lanes. L2 is never invalidated
// -> the per-step 384 KB weight stream stays L2-warm (the ~10 us/step cold-LLC restream
// that r8-r17 paid disappears). WAR discipline identical to the r14-proven protocol.
#define SPB2 16
#define HSTR 520

#define LOADW(buf, g)                                                            \
  {                                                                              \
    const _Float16* _s = packW +                                                 \
        (((size_t)(ng * 24 + (g) * 8 + wid)) * 16) * 512 + (size_t)lane * 8;     \
    _Pragma("unroll")                                                            \
    for (int kc = 0; kc < 16; ++kc)                                              \
      buf[kc] = *reinterpret_cast<const f16x8*>(_s + (size_t)kc * 512);          \
  }

#define MF16(buf, acc)                                                           \
  {                                                                              \
    _Pragma("unroll")                                                            \
    for (int kc = 0; kc < 16; ++kc) {                                            \
      f16x8 _ha = *reinterpret_cast<const f16x8*>(&hs[arow][kc * 32 + agrp * 8]); \
      acc = __builtin_amdgcn_mfma_f32_16x16x32_f16(_ha, buf[kc], acc, 0, 0, 0);  \
    }                                                                            \
  }

__global__ __launch_bounds__(512, 2) void gru_scan_mfma(
    const float* __restrict__ gi,      // [NSEQ][TT][G3]
    const _Float16* __restrict__ packW,
    const float* __restrict__ bhh,     // [G3]
    float* __restrict__ hfin,          // [NSEQ][HH]
    _Float16* __restrict__ yout,       // [NSEQ][TT][HH] fp16 or nullptr
    _Float16* __restrict__ hx,         // [2][NSEQ][HH] exchange (LLC-only via sc0/sc1)
    unsigned int* __restrict__ flags)  // [SGRP][NGRP][TT], zeroed pre-launch
{
  __shared__ __align__(16) _Float16 hs[SPB2][HSTR];   // 16.6 KB

  const int tid = threadIdx.x;
  const int lane = tid & 63;
  const int wid = tid >> 6;                   // 0..7
  const int bid = blockIdx.x;
  const int sg = bid >> 2;                    // seq group
  const int ng = bid & 3;                     // N group (uniform per XCD: 8 % 4 == 0)
  const int seq0 = sg * SPB2;

  const int arow = lane & 15;
  const int agrp = lane >> 4;
  const int dcol = lane & 15;
  const int mrow = (lane >> 4) * 4;

  const int cg = ng * 128 + wid * 16 + dcol;

  const float bhr = bhh[cg];
  const float bhz = bhh[HH + cg];
  const float bhn = bhh[2 * HH + cg];

  float hold[4] = {0.f, 0.f, 0.f, 0.f};

  for (int e = tid; e < SPB2 * HSTR; e += 512)
    hs[e / HSTR][e % HSTR] = (_Float16)0.f;
  __syncthreads();

  for (int t = 0; t < TT; ++t) {
    if (t > 0) {
      // 4 relaxed poller lanes, one per producer (separate 256 B flag rows; no inv)
      if (tid < NGRP) {
        const unsigned int* fp = &flags[((size_t)sg * NGRP + tid) * TT + (t - 1)];
        while (__hip_atomic_load(fp, __ATOMIC_RELAXED, __HIP_MEMORY_SCOPE_AGENT) == 0u) {}
      }
      __syncthreads();
      // copy h(t-1) from hx[t&1] via sc0/sc1 BYPASS loads (LLC-direct, cache-proof)
      {
        const _Float16* src = hx + (size_t)(t & 1) * NSEQ * HH
                              + (size_t)seq0 * HH + (size_t)tid * 16;
        f16x8 v0, v1;
        asm volatile(
            "global_load_dwordx4 %0, %2, off sc0 sc1\n\t"
            "global_load_dwordx4 %1, %2, off offset:16 sc0 sc1\n\t"
            "s_waitcnt vmcnt(0)"
            : "=&v"(v0), "=&v"(v1) : "v"(src) : "memory");
        int e0 = tid * 16;
        int row = e0 >> 9;
        int col = e0 & 511;
        *reinterpret_cast<f16x8*>(&hs[row][col]) = v0;
        *reinterpret_cast<f16x8*>(&hs[row][col + 8]) = v1;
      }
      __syncthreads();
    }

    float gir[4], giz[4], gin[4];
#pragma unroll
    for (int r = 0; r < 4; ++r) {
      const float* p0 = gi + ((size_t)(seq0 + mrow + r) * TT + t) * G3;
      gir[r] = p0[cg];
      giz[r] = p0[HH + cg];
      gin[r] = p0[2 * HH + cg];
    }

    f16x8 bufA[16], bufB[16];
    f32x4 aR = {0.f,0.f,0.f,0.f}, aZ = {0.f,0.f,0.f,0.f}, aN = {0.f,0.f,0.f,0.f};
    LOADW(bufA, 0)
    LOADW(bufB, 1)
    MF16(bufA, aR)
    LOADW(bufA, 2)
    MF16(bufB, aZ)
    MF16(bufA, aN)

    const int nb = (t + 1) & 1;
#pragma unroll
    for (int r = 0; r < 4; ++r) {
      float hr = aR[r] + bhr;
      float hz = aZ[r] + bhz;
      float hn = aN[r] + bhn;
      float rr = __builtin_amdgcn_rcpf(1.f + __expf(-(gir[r] + hr)));
      float zz = __builtin_amdgcn_rcpf(1.f + __expf(-(giz[r] + hz)));
      float ex = __expf(2.f * (gin[r] + rr * hn));
      float nn = 1.f - 2.f * __builtin_amdgcn_rcpf(ex + 1.f);
      float hnew = nn + zz * (hold[r] - nn);
      hold[r] = hnew;
      // hx store: sc0/sc1 write-through to LLC (no dirty L2, no wbl2 needed)
      {
        _Float16 h16 = (_Float16)hnew;
        unsigned int hv32 = (unsigned int)__builtin_bit_cast(unsigned short, h16);
        _Float16* addr = hx + (size_t)nb * NSEQ * HH
                         + (size_t)(seq0 + mrow + r) * HH + cg;
        asm volatile("global_store_short %0, %1, off sc0 sc1"
                     :: "v"(addr), "v"(hv32) : "memory");
      }
      if (yout)
        yout[((size_t)(seq0 + mrow + r) * TT + t) * HH + cg] = (_Float16)hnew;
    }

    // publish: drain stores to LLC, barrier, relaxed flag store (no release-inv)
    asm volatile("s_waitcnt vmcnt(0)" ::: "memory");
    __syncthreads();
    if (tid == 0)
      __hip_atomic_store(&flags[((size_t)sg * NGRP + ng) * TT + t], 1u,
                         __ATOMIC_RELAXED, __HIP_MEMORY_SCOPE_AGENT);
  }

#pragma unroll
  for (int r = 0; r < 4; ++r)
    hfin[(size_t)(seq0 + mrow + r) * HH + cg] = hold[r];
}

// ---------------- fallback fp32 scan (row-streaming) ----------------
#define QS 4
#define SCTH 512
__global__ __launch_bounds__(SCTH) void gru_scan2f(
    const float* __restrict__ gi, const float* __restrict__ W,
    const float* __restrict__ bhh, float* __restrict__ hfin,
    float* __restrict__ yout)
{
  __shared__ __align__(16) float hsl[HH][QS];
  const int col = threadIdx.x;
  const int seq0 = blockIdx.x * QS;
  const float bh0 = bhh[col];
  const float bh1 = bhh[HH + col];
  const float bh2 = bhh[2 * HH + col];
  const float* w0p = W + (size_t)col * HH;
  const float* w1p = W + (size_t)(HH + col) * HH;
  const float* w2p = W + (size_t)(2 * HH + col) * HH;

  *reinterpret_cast<float4*>(&hsl[col][0]) = make_float4(0.f, 0.f, 0.f, 0.f);
  __syncthreads();

  for (int t = 0; t < TT; ++t) {
    float acc0[QS], acc1[QS], acc2[QS];
#pragma unroll
    for (int s = 0; s < QS; ++s) { acc0[s] = bh0; acc1[s] = bh1; acc2[s] = bh2; }
    float4 ho = *reinterpret_cast<const float4*>(&hsl[col][0]);
    float hold[QS] = {ho.x, ho.y, ho.z, ho.w};
#pragma unroll 2
    for (int k0 = 0; k0 < HH; k0 += 4) {
      float w[3][4];
      float4 a = *reinterpret_cast<const float4*>(&w0p[k0]);
      w[0][0] = a.x; w[0][1] = a.y; w[0][2] = a.z; w[0][3] = a.w;
      float4 b = *reinterpret_cast<const float4*>(&w1p[k0]);
      w[1][0] = b.x; w[1][1] = b.y; w[1][2] = b.z; w[1][3] = b.w;
      float4 c = *reinterpret_cast<const float4*>(&w2p[k0]);
      w[2][0] = c.x; w[2][1] = c.y; w[2][2] = c.z; w[2][3] = c.w;
#pragma unroll
      for (int kk = 0; kk < 4; ++kk) {
        float4 h4 = *reinterpret_cast<const float4*>(&hsl[k0 + kk][0]);
        float hq[4] = {h4.x, h4.y, h4.z, h4.w};
#pragma unroll
        for (int s = 0; s < QS; ++s) {
          acc0[s] = fmaf(hq[s], w[0][kk], acc0[s]);
          acc1[s] = fmaf(hq[s], w[1][kk], acc1[s]);
          acc2[s] = fmaf(hq[s], w[2][kk], acc2[s]);
        }
      }
    }
    __syncthreads();
    float hnew[QS];
#pragma unroll
    for (int s = 0; s < QS; ++s) {
      size_t grow = ((size_t)(seq0 + s) * TT + t) * G3;
      float ir = gi[grow + col];
      float iz = gi[grow + HH + col];
      float inn = gi[grow + 2 * HH + col];
      float r = 1.f / (1.f + expf(-(ir + acc0[s])));
      float z = 1.f / (1.f + expf(-(iz + acc1[s])));
      float nn = tanhf(inn + r * acc2[s]);
      hnew[s] = (1.f - z) * nn + z * hold[s];
      if (yout) yout[((size_t)(seq0 + s) * TT + t) * HH + col] = hnew[s];
    }
    *reinterpret_cast<float4*>(&hsl[col][0]) =
        make_float4(hnew[0], hnew[1], hnew[2], hnew[3]);
    __syncthreads();
  }
#pragma unroll
  for (int s = 0; s < QS; ++s)
    hfin[(size_t)(seq0 + s) * HH + col] = hsl[col][s];
}

// ---------------- final FC + channel mean ----------------
__global__ __launch_bounds__(256) void fc_mean(
    const float* __restrict__ hfin, const float* __restrict__ fcW,
    const float* __restrict__ fcb, float* __restrict__ out)
{
  __shared__ float red[256];
  const int b = blockIdx.x;
  const int tid = threadIdx.x;
  float sum = 0.f;
  for (int e = tid; e < CC * HH; e += 256) {
    int c = e >> 9;
    int k = e & (HH - 1);
    sum += hfin[(size_t)(b * CC + c) * HH + k] * fcW[k];
  }
  red[tid] = sum;
  __syncthreads();
  for (int w = 128; w > 0; w >>= 1) {
    if (tid < w) red[tid] += red[tid + w];
    __syncthreads();
  }
  if (tid == 0) out[b] = red[0] * (1.f / CC) + fcb[0];
}

extern "C" void kernel_launch(void* const* d_in, const int* in_sizes, int n_in,
                              void* d_out, int out_size, void* d_ws, size_t ws_size,
                              hipStream_t stream)
{
  const float* x    = (const float*)d_in[0];
  const float* Wih0 = (const float*)d_in[1];
  const float* Whh0 = (const float*)d_in[2];
  const float* bih0 = (const float*)d_in[3];
  const float* bhh0 = (const float*)d_in[4];
  const float* Wih1 = (const float*)d_in[5];
  const float* Whh1 = (const float*)d_in[6];
  const float* bih1 = (const float*)d_in[7];
  const float* bhh1 = (const float*)d_in[8];
  const float* fcW  = (const float*)d_in[9];
  const float* fcb  = (const float*)d_in[10];
  float* out = (float*)d_out;

  // ws layout (fast path):
  //   gi    [MROWS][G3] fp32  100,663,296 @ 0
  //   y0h   [MROWS][HH] fp16   16,777,216 @ 100,663,296
  //   xh    [MROWS][FF] fp16    8,388,608 @ 117,440,512
  //   pWih  fp16 (K<=512)       1,572,864 @ 125,829,120
  //   pWhh  fp16                1,572,864 @ 127,401,984
  //   hx    [2][NSEQ][HH] fp16    524,288 @ 128,974,848
  //   flags [SGRP][NGRP][TT]       16,384 @ 129,499,136
  //   hfin  [NSEQ][HH] fp32       524,288 @ 134,217,728  (shared w/ fallback layout)
  char* ws = (char*)d_ws;
  float* gibuf = (float*)ws;
  _Float16* y0h  = (_Float16*)(ws + 100663296ull);
  _Float16* xh   = (_Float16*)(ws + 117440512ull);
  _Float16* pWih = (_Float16*)(ws + 125829120ull);
  _Float16* pWhh = (_Float16*)(ws + 127401984ull);
  _Float16* hx   = (_Float16*)(ws + 128974848ull);
  unsigned int* flags = (unsigned int*)(ws + 129499136ull);
  float* hfin = (float*)(ws + 134217728ull);
  float* y0f  = (float*)(ws + 100663296ull);   // fallback fp32 y0 (33.5 MB)
  const bool mfma_ok = (ws_size >= 134742016ull);

  if (mfma_ok) {
    // layer 0: x->fp16, pack Wih0, MFMA GEMM (K=256)
    conv16<<<dim3((MROWS * FF / 8 + 255) / 256), 256, 0, stream>>>(x, xh, MROWS * FF / 8);
    pack_wih<<<dim3(192), 256, 0, stream>>>(Wih0, pWih, FF);
    gemm_mfma<<<dim3(12, 128), 256, 0, stream>>>(xh, pWih, bih0, gibuf, FF);

    // layer 0 scan
    pack_whh<<<dim3(384), 256, 0, stream>>>(Whh0, pWhh);
    hipMemsetAsync(flags, 0, SGRP * NGRP * TT * sizeof(unsigned int), stream);
    gru_scan_mfma<<<dim3(SGRP * NGRP), 512, 0, stream>>>(gibuf, pWhh, bhh0, hfin, y0h, hx, flags);

    // layer 1: pack Wih1, MFMA GEMM (K=512) on fp16 y0
    pack_wih<<<dim3(384), 256, 0, stream>>>(Wih1, pWih, HH);
    gemm_mfma<<<dim3(12, 128), 256, 0, stream>>>(y0h, pWih, bih1, gibuf, HH);

    // layer 1 scan
    pack_whh<<<dim3(384), 256, 0, stream>>>(Whh1, pWhh);
    hipMemsetAsync(flags, 0, SGRP * NGRP * TT * sizeof(unsigned int), stream);
    gru_scan_mfma<<<dim3(SGRP * NGRP), 512, 0, stream>>>(gibuf, pWhh, bhh1, hfin, nullptr, hx, flags);
  } else {
    gemm_bias<<<dim3(G3 / TNg, MROWS / TMg), 256, 0, stream>>>(x, Wih0, bih0, gibuf, MROWS, G3, FF);
    gru_scan2f<<<dim3(NSEQ / QS), SCTH, 0, stream>>>(gibuf, Whh0, bhh0, hfin, y0f);
    gemm_bias<<<dim3(G3 / TNg, MROWS / TMg), 256, 0, stream>>>(y0f, Wih1, bih1, gibuf, MROWS, G3, HH);
    gru_scan2f<<<dim3(NSEQ / QS), SCTH, 0, stream>>>(gibuf, Whh1, bhh1, hfin, nullptr);
  }

  fc_mean<<<dim3(BB), 256, 0, stream>>>(hfin, fcW, fcb, out);
}

// Round 20
// 618.706 us; speedup vs baseline: 6.0788x; 1.5314x over previous
//
#include <hip/hip_runtime.h>
#include <math.h>

// Problem dims (fixed by reference)
#define BB 32
#define CC 8
#define TT 64
#define FF 256
#define HH 512
#define G3 1536
#define NSEQ 256            // BB*CC
#define MROWS 16384         // NSEQ*TT

#define SGRP 16             // sequence groups (16 seqs each)
#define NGRP 4              // N-split ways (384 preact cols each)

typedef _Float16 f16x8 __attribute__((ext_vector_type(8)));
typedef float f32x4 __attribute__((ext_vector_type(4)));

// ---------------- fallback fp32 input GEMM ----------------
#define TMg 128
#define TNg 128
#define TKg 16

__global__ __launch_bounds__(256) void gemm_bias(
    const float* __restrict__ A, const float* __restrict__ W,
    const float* __restrict__ bias, float* __restrict__ C,
    int M, int N, int K)
{
  __shared__ float As[TKg][TMg + 4];
  __shared__ float Ws[TKg][TNg + 4];
  const int bm = blockIdx.y * TMg;
  const int bn = blockIdx.x * TNg;
  const int tid = threadIdx.x;
  const int tx = tid & 15;
  const int ty = tid >> 4;
  float acc[8][8];
#pragma unroll
  for (int i = 0; i < 8; ++i)
#pragma unroll
    for (int j = 0; j < 8; ++j) acc[i][j] = 0.f;

  for (int k0 = 0; k0 < K; k0 += TKg) {
    __syncthreads();
#pragma unroll
    for (int i = 0; i < 8; ++i) {
      int e = i * 256 + tid;
      int r = e >> 4;
      int c = e & 15;
      As[c][r] = A[(size_t)(bm + r) * K + (k0 + c)];
      Ws[c][r] = W[(size_t)(bn + r) * K + (k0 + c)];
    }
    __syncthreads();
#pragma unroll
    for (int k = 0; k < TKg; ++k) {
      float a[8], w[8];
#pragma unroll
      for (int i = 0; i < 8; ++i) a[i] = As[k][ty * 8 + i];
#pragma unroll
      for (int j = 0; j < 8; ++j) w[j] = Ws[k][tx + 16 * j];
#pragma unroll
      for (int i = 0; i < 8; ++i)
#pragma unroll
        for (int j = 0; j < 8; ++j) acc[i][j] = fmaf(a[i], w[j], acc[i][j]);
    }
  }
#pragma unroll
  for (int i = 0; i < 8; ++i) {
    size_t m = (size_t)(bm + ty * 8 + i);
#pragma unroll
    for (int j = 0; j < 8; ++j) {
      int n = bn + tx + 16 * j;
      C[m * N + n] = acc[i][j] + bias[n];
    }
  }
}

// ---------------- fp32 -> fp16 convert (vectorized x8) ----------------
__global__ __launch_bounds__(256) void conv16(
    const float* __restrict__ x, _Float16* __restrict__ xh, int n8)
{
  int i = blockIdx.x * 256 + threadIdx.x;
  if (i < n8) {
    float4 a = reinterpret_cast<const float4*>(x)[i * 2];
    float4 b = reinterpret_cast<const float4*>(x)[i * 2 + 1];
    f16x8 v;
    v[0] = (_Float16)a.x; v[1] = (_Float16)a.y; v[2] = (_Float16)a.z; v[3] = (_Float16)a.w;
    v[4] = (_Float16)b.x; v[5] = (_Float16)b.y; v[6] = (_Float16)b.z; v[7] = (_Float16)b.w;
    reinterpret_cast<f16x8*>(xh)[i] = v;
  }
}

// ---------------- pack W[G3][K] fp32 -> fp16 B-fragments ----------------
// P[tile(96)][kc(K/32)][lane(64)][8]; B-frag: n=lane&15 (W row in tile), k=kc*32+(lane>>4)*8+i
__global__ __launch_bounds__(256) void pack_wih(
    const float* __restrict__ W, _Float16* __restrict__ P, int K)
{
  int id = blockIdx.x * 256 + threadIdx.x;
  int lane = id & 63;
  int kcs = K >> 5;
  int t6 = id >> 6;
  int kc = t6 % kcs;
  int tile = t6 / kcs;
  if (tile >= 96) return;
  int row = tile * 16 + (lane & 15);
  int k0 = kc * 32 + ((lane >> 4) * 8);
  const float* src = W + (size_t)row * K + k0;
  f16x8 v;
#pragma unroll
  for (int i = 0; i < 8; ++i) v[i] = (_Float16)src[i];
  *reinterpret_cast<f16x8*>(P + (size_t)id * 8) = v;
}

// ---------------- pack Whh[G3][HH] -> fp16 B-fragments, 4-way N-split order ------
// P[ng(4)][tl(24)][kc(16)][lane(64)][8]; tl = gate*8 + sub; global tile = gate*32+ng*8+sub
__global__ __launch_bounds__(256) void pack_whh(
    const float* __restrict__ W, _Float16* __restrict__ P)
{
  int id = blockIdx.x * 256 + threadIdx.x;    // 0 .. 98303
  int lane = id & 63;
  int kc = (id >> 6) & 15;
  int tidx = id >> 10;                        // 0..95 = ng*24 + tl
  int ng = tidx / 24;
  int tl = tidx % 24;
  int g = tl >> 3, sub = tl & 7;
  int gt = g * 32 + ng * 8 + sub;
  int row = gt * 16 + (lane & 15);
  int k0 = kc * 32 + ((lane >> 4) * 8);
  const float* src = W + (size_t)row * HH + k0;
  f16x8 v;
#pragma unroll
  for (int i = 0; i < 8; ++i) v[i] = (_Float16)src[i];
  *reinterpret_cast<f16x8*>(P + (size_t)id * 8) = v;
}

// ---------------- MFMA input GEMM (r14-proven): C = A(fp16) @ Wpack^T + bias ----------
__device__ __forceinline__ void gload16g(const _Float16* g, _Float16* l) {
  __builtin_amdgcn_global_load_lds(
      (const __attribute__((address_space(1))) unsigned int*)g,
      (__attribute__((address_space(3))) unsigned int*)l, 16, 0, 0);
}

__global__ __launch_bounds__(256, 2) void gemm_mfma(
    const _Float16* __restrict__ A,   // [MROWS][K] fp16
    const _Float16* __restrict__ Bp,  // packed [96][K/32][64][8]
    const float* __restrict__ bias,   // [G3]
    float* __restrict__ C,            // [MROWS][G3]
    int K)
{
  __shared__ __align__(16) _Float16 As[2][128][36];   // 18.4 KB padded
  __shared__ __align__(16) _Float16 Bs[2][8 * 512];   // 16 KB (frag order)

  const int tid = threadIdx.x;
  const int lane = tid & 63;
  const int wv = tid >> 6;
  const int wm = wv >> 1, wn = wv & 1;
  const int bnT = blockIdx.x * 8;             // first of 8 n-tiles
  const int bm = blockIdx.y * 128;
  const int kcs = K >> 5;

  const int arow = lane & 15;
  const int agrp = lane >> 4;
  const int dcol = lane & 15;
  const int mrow = (lane >> 4) * 4;

  f32x4 acc[4][4];
#pragma unroll
  for (int i = 0; i < 4; ++i)
#pragma unroll
    for (int j = 0; j < 4; ++j) acc[i][j] = (f32x4){0.f, 0.f, 0.f, 0.f};

  auto stageA = [&](int s, int b) {
#pragma unroll
    for (int p = 0; p < 2; ++p) {
      int idx = p * 256 + tid;
      int row = idx >> 2;
      int cs = idx & 3;
      f16x8 v = *reinterpret_cast<const f16x8*>(
          A + (size_t)(bm + row) * K + s * 32 + cs * 8);
      *reinterpret_cast<f16x8*>(&As[b][row][cs * 8]) = v;
    }
  };
  auto stageB = [&](int s, int b) {
#pragma unroll
    for (int q = 0; q < 2; ++q) {
      int nt = wv * 2 + q;
      const _Float16* src = Bp + ((size_t)((bnT + nt) * kcs + s) * 64 + lane) * 8;
      gload16g(src, &Bs[b][nt * 512]);
    }
  };

  stageA(0, 0);
  stageB(0, 0);
  __syncthreads();

  for (int s = 0; s < kcs; ++s) {
    const int b = s & 1;
    if (s + 1 < kcs) {
      stageA(s + 1, b ^ 1);
      stageB(s + 1, b ^ 1);
    }
    f16x8 af[4], bf[4];
#pragma unroll
    for (int mt = 0; mt < 4; ++mt)
      af[mt] = *reinterpret_cast<const f16x8*>(&As[b][wm * 64 + mt * 16 + arow][agrp * 8]);
#pragma unroll
    for (int nt = 0; nt < 4; ++nt)
      bf[nt] = *reinterpret_cast<const f16x8*>(&Bs[b][(wn * 4 + nt) * 512 + lane * 8]);
#pragma unroll
    for (int mt = 0; mt < 4; ++mt)
#pragma unroll
      for (int nt = 0; nt < 4; ++nt)
        acc[mt][nt] = __builtin_amdgcn_mfma_f32_16x16x32_f16(af[mt], bf[nt], acc[mt][nt], 0, 0, 0);
    __syncthreads();
  }

  // ---- epilogue: bias + store ----
#pragma unroll
  for (int nt = 0; nt < 4; ++nt) {
    const int n = (bnT + wn * 4 + nt) * 16 + dcol;
    const float bv = bias[n];
#pragma unroll
    for (int mt = 0; mt < 4; ++mt) {
      const size_t m0 = (size_t)(bm + wm * 64 + mt * 16 + mrow);
#pragma unroll
      for (int r = 0; r < 4; ++r)
        C[(m0 + r) * G3 + n] = acc[mt][nt][r] + bv;
    }
  }
}

// ---------------- MFMA recurrent scan: sc0/sc1 fenceless + REGISTER-RESIDENT weights --
// r18-proven fenceless protocol (sc0/sc1 LLC-bypass hx, relaxed flags, no invalidates).
// NEW: __launch_bounds__(512,1) lifts the VGPR cap to 256 (64 blocks on 256 CUs = 1
// block/CU, so occupancy is unaffected), letting each wave hold its 3 weight tiles
// (192 VGPR) in registers for ALL 64 steps -> zero per-step weight traffic. Worst case
// (allocator squeezes) the loads rematerialize from warm L2 == r18 behavior.
// gi loads issue BEFORE the poll (prev-kernel data, independent of hx).
#define SPB2 16
#define HSTR 520

#define LOADW(buf, g)                                                            \
  {                                                                              \
    const _Float16* _s = packW +                                                 \
        (((size_t)(ng * 24 + (g) * 8 + wid)) * 16) * 512 + (size_t)lane * 8;     \
    _Pragma("unroll")                                                            \
    for (int kc = 0; kc < 16; ++kc)                                              \
      buf[kc] = *reinterpret_cast<const f16x8*>(_s + (size_t)kc * 512);          \
  }

#define MF16(buf, acc)                                                           \
  {                                                                              \
    _Pragma("unroll")                                                            \
    for (int kc = 0; kc < 16; ++kc) {                                            \
      f16x8 _ha = *reinterpret_cast<const f16x8*>(&hs[arow][kc * 32 + agrp * 8]); \
      acc = __builtin_amdgcn_mfma_f32_16x16x32_f16(_ha, buf[kc], acc, 0, 0, 0);  \
    }                                                                            \
  }

__global__ __launch_bounds__(512, 1) void gru_scan_mfma(
    const float* __restrict__ gi,      // [NSEQ][TT][G3]
    const _Float16* __restrict__ packW,
    const float* __restrict__ bhh,     // [G3]
    float* __restrict__ hfin,          // [NSEQ][HH]
    _Float16* __restrict__ yout,       // [NSEQ][TT][HH] fp16 or nullptr
    _Float16* __restrict__ hx,         // [2][NSEQ][HH] exchange (LLC-only via sc0/sc1)
    unsigned int* __restrict__ flags)  // [SGRP][NGRP][TT], zeroed pre-launch
{
  __shared__ __align__(16) _Float16 hs[SPB2][HSTR];   // 16.6 KB

  const int tid = threadIdx.x;
  const int lane = tid & 63;
  const int wid = tid >> 6;                   // 0..7
  const int bid = blockIdx.x;
  const int sg = bid >> 2;                    // seq group
  const int ng = bid & 3;                     // N group (uniform per XCD: 8 % 4 == 0)
  const int seq0 = sg * SPB2;

  const int arow = lane & 15;
  const int agrp = lane >> 4;
  const int dcol = lane & 15;
  const int mrow = (lane >> 4) * 4;

  const int cg = ng * 128 + wid * 16 + dcol;

  const float bhr = bhh[cg];
  const float bhz = bhh[HH + cg];
  const float bhn = bhh[2 * HH + cg];

  // ---- persistent weight fragments: 3 tiles x 64 VGPR = 192 VGPR, loaded ONCE ----
  f16x8 wbR[16], wbZ[16], wbN[16];
  LOADW(wbR, 0)
  LOADW(wbZ, 1)
  LOADW(wbN, 2)

  float hold[4] = {0.f, 0.f, 0.f, 0.f};

  for (int e = tid; e < SPB2 * HSTR; e += 512)
    hs[e / HSTR][e % HSTR] = (_Float16)0.f;
  __syncthreads();

  for (int t = 0; t < TT; ++t) {
    // ---- gi loads: prev-kernel data, independent of hx -> issue BEFORE the poll ----
    float gir[4], giz[4], gin[4];
#pragma unroll
    for (int r = 0; r < 4; ++r) {
      const float* p0 = gi + ((size_t)(seq0 + mrow + r) * TT + t) * G3;
      gir[r] = p0[cg];
      giz[r] = p0[HH + cg];
      gin[r] = p0[2 * HH + cg];
    }

    if (t > 0) {
      // 4 relaxed poller lanes, one per producer (separate flag rows; no invalidates)
      if (tid < NGRP) {
        const unsigned int* fp = &flags[((size_t)sg * NGRP + tid) * TT + (t - 1)];
        while (__hip_atomic_load(fp, __ATOMIC_RELAXED, __HIP_MEMORY_SCOPE_AGENT) == 0u) {}
      }
      __syncthreads();
      // copy h(t-1) from hx[t&1] via sc0/sc1 BYPASS loads (LLC-direct, cache-proof)
      {
        const _Float16* src = hx + (size_t)(t & 1) * NSEQ * HH
                              + (size_t)seq0 * HH + (size_t)tid * 16;
        f16x8 v0, v1;
        asm volatile(
            "global_load_dwordx4 %0, %2, off sc0 sc1\n\t"
            "global_load_dwordx4 %1, %2, off offset:16 sc0 sc1\n\t"
            "s_waitcnt vmcnt(0)"
            : "=&v"(v0), "=&v"(v1) : "v"(src) : "memory");
        int e0 = tid * 16;
        int row = e0 >> 9;
        int col = e0 & 511;
        *reinterpret_cast<f16x8*>(&hs[row][col]) = v0;
        *reinterpret_cast<f16x8*>(&hs[row][col + 8]) = v1;
      }
      __syncthreads();
    }

    f32x4 aR = {0.f,0.f,0.f,0.f}, aZ = {0.f,0.f,0.f,0.f}, aN = {0.f,0.f,0.f,0.f};
    MF16(wbR, aR)
    MF16(wbZ, aZ)
    MF16(wbN, aN)

    const int nb = (t + 1) & 1;
#pragma unroll
    for (int r = 0; r < 4; ++r) {
      float hr = aR[r] + bhr;
      float hz = aZ[r] + bhz;
      float hn = aN[r] + bhn;
      float rr = __builtin_amdgcn_rcpf(1.f + __expf(-(gir[r] + hr)));
      float zz = __builtin_amdgcn_rcpf(1.f + __expf(-(giz[r] + hz)));
      float ex = __expf(2.f * (gin[r] + rr * hn));
      float nn = 1.f - 2.f * __builtin_amdgcn_rcpf(ex + 1.f);
      float hnew = nn + zz * (hold[r] - nn);
      hold[r] = hnew;
      // hx store: sc0/sc1 write-through to LLC (no dirty L2)
      {
        _Float16 h16 = (_Float16)hnew;
        unsigned int hv32 = (unsigned int)__builtin_bit_cast(unsigned short, h16);
        _Float16* addr = hx + (size_t)nb * NSEQ * HH
                         + (size_t)(seq0 + mrow + r) * HH + cg;
        asm volatile("global_store_short %0, %1, off sc0 sc1"
                     :: "v"(addr), "v"(hv32) : "memory");
      }
      if (yout)
        yout[((size_t)(seq0 + mrow + r) * TT + t) * HH + cg] = (_Float16)hnew;
    }

    // publish: drain stores to LLC, barrier, relaxed flag store
    asm volatile("s_waitcnt vmcnt(0)" ::: "memory");
    __syncthreads();
    if (tid == 0)
      __hip_atomic_store(&flags[((size_t)sg * NGRP + ng) * TT + t], 1u,
                         __ATOMIC_RELAXED, __HIP_MEMORY_SCOPE_AGENT);
  }

#pragma unroll
  for (int r = 0; r < 4; ++r)
    hfin[(size_t)(seq0 + mrow + r) * HH + cg] = hold[r];
}

// ---------------- fallback fp32 scan (row-streaming) ----------------
#define QS 4
#define SCTH 512
__global__ __launch_bounds__(SCTH) void gru_scan2f(
    const float* __restrict__ gi, const float* __restrict__ W,
    const float* __restrict__ bhh, float* __restrict__ hfin,
    float* __restrict__ yout)
{
  __shared__ __align__(16) float hsl[HH][QS];
  const int col = threadIdx.x;
  const int seq0 = blockIdx.x * QS;
  const float bh0 = bhh[col];
  const float bh1 = bhh[HH + col];
  const float bh2 = bhh[2 * HH + col];
  const float* w0p = W + (size_t)col * HH;
  const float* w1p = W + (size_t)(HH + col) * HH;
  const float* w2p = W + (size_t)(2 * HH + col) * HH;

  *reinterpret_cast<float4*>(&hsl[col][0]) = make_float4(0.f, 0.f, 0.f, 0.f);
  __syncthreads();

  for (int t = 0; t < TT; ++t) {
    float acc0[QS], acc1[QS], acc2[QS];
#pragma unroll
    for (int s = 0; s < QS; ++s) { acc0[s] = bh0; acc1[s] = bh1; acc2[s] = bh2; }
    float4 ho = *reinterpret_cast<const float4*>(&hsl[col][0]);
    float hold[QS] = {ho.x, ho.y, ho.z, ho.w};
#pragma unroll 2
    for (int k0 = 0; k0 < HH; k0 += 4) {
      float w[3][4];
      float4 a = *reinterpret_cast<const float4*>(&w0p[k0]);
      w[0][0] = a.x; w[0][1] = a.y; w[0][2] = a.z; w[0][3] = a.w;
      float4 b = *reinterpret_cast<const float4*>(&w1p[k0]);
      w[1][0] = b.x; w[1][1] = b.y; w[1][2] = b.z; w[1][3] = b.w;
      float4 c = *reinterpret_cast<const float4*>(&w2p[k0]);
      w[2][0] = c.x; w[2][1] = c.y; w[2][2] = c.z; w[2][3] = c.w;
#pragma unroll
      for (int kk = 0; kk < 4; ++kk) {
        float4 h4 = *reinterpret_cast<const float4*>(&hsl[k0 + kk][0]);
        float hq[4] = {h4.x, h4.y, h4.z, h4.w};
#pragma unroll
        for (int s = 0; s < QS; ++s) {
          acc0[s] = fmaf(hq[s], w[0][kk], acc0[s]);
          acc1[s] = fmaf(hq[s], w[1][kk], acc1[s]);
          acc2[s] = fmaf(hq[s], w[2][kk], acc2[s]);
        }
      }
    }
    __syncthreads();
    float hnew[QS];
#pragma unroll
    for (int s = 0; s < QS; ++s) {
      size_t grow = ((size_t)(seq0 + s) * TT + t) * G3;
      float ir = gi[grow + col];
      float iz = gi[grow + HH + col];
      float inn = gi[grow + 2 * HH + col];
      float r = 1.f / (1.f + expf(-(ir + acc0[s])));
      float z = 1.f / (1.f + expf(-(iz + acc1[s])));
      float nn = tanhf(inn + r * acc2[s]);
      hnew[s] = (1.f - z) * nn + z * hold[s];
      if (yout) yout[((size_t)(seq0 + s) * TT + t) * HH + col] = hnew[s];
    }
    *reinterpret_cast<float4*>(&hsl[col][0]) =
        make_float4(hnew[0], hnew[1], hnew[2], hnew[3]);
    __syncthreads();
  }
#pragma unroll
  for (int s = 0; s < QS; ++s)
    hfin[(size_t)(seq0 + s) * HH + col] = hsl[col][s];
}

// ---------------- final FC + channel mean ----------------
__global__ __launch_bounds__(256) void fc_mean(
    const float* __restrict__ hfin, const float* __restrict__ fcW,
    const float* __restrict__ fcb, float* __restrict__ out)
{
  __shared__ float red[256];
  const int b = blockIdx.x;
  const int tid = threadIdx.x;
  float sum = 0.f;
  for (int e = tid; e < CC * HH; e += 256) {
    int c = e >> 9;
    int k = e & (HH - 1);
    sum += hfin[(size_t)(b * CC + c) * HH + k] * fcW[k];
  }
  red[tid] = sum;
  __syncthreads();
  for (int w = 128; w > 0; w >>= 1) {
    if (tid < w) red[tid] += red[tid + w];
    __syncthreads();
  }
  if (tid == 0) out[b] = red[0] * (1.f / CC) + fcb[0];
}

extern "C" void kernel_launch(void* const* d_in, const int* in_sizes, int n_in,
                              void* d_out, int out_size, void* d_ws, size_t ws_size,
                              hipStream_t stream)
{
  const float* x    = (const float*)d_in[0];
  const float* Wih0 = (const float*)d_in[1];
  const float* Whh0 = (const float*)d_in[2];
  const float* bih0 = (const float*)d_in[3];
  const float* bhh0 = (const float*)d_in[4];
  const float* Wih1 = (const float*)d_in[5];
  const float* Whh1 = (const float*)d_in[6];
  const float* bih1 = (const float*)d_in[7];
  const float* bhh1 = (const float*)d_in[8];
  const float* fcW  = (const float*)d_in[9];
  const float* fcb  = (const float*)d_in[10];
  float* out = (float*)d_out;

  // ws layout (fast path):
  //   gi    [MROWS][G3] fp32  100,663,296 @ 0
  //   y0h   [MROWS][HH] fp16   16,777,216 @ 100,663,296
  //   xh    [MROWS][FF] fp16    8,388,608 @ 117,440,512
  //   pWih  fp16 (K<=512)       1,572,864 @ 125,829,120
  //   pWhh  fp16                1,572,864 @ 127,401,984
  //   hx    [2][NSEQ][HH] fp16    524,288 @ 128,974,848
  //   flags [SGRP][NGRP][TT]       16,384 @ 129,499,136
  //   hfin  [NSEQ][HH] fp32       524,288 @ 134,217,728  (shared w/ fallback layout)
  char* ws = (char*)d_ws;
  float* gibuf = (float*)ws;
  _Float16* y0h  = (_Float16*)(ws + 100663296ull);
  _Float16* xh   = (_Float16*)(ws + 117440512ull);
  _Float16* pWih = (_Float16*)(ws + 125829120ull);
  _Float16* pWhh = (_Float16*)(ws + 127401984ull);
  _Float16* hx   = (_Float16*)(ws + 128974848ull);
  unsigned int* flags = (unsigned int*)(ws + 129499136ull);
  float* hfin = (float*)(ws + 134217728ull);
  float* y0f  = (float*)(ws + 100663296ull);   // fallback fp32 y0 (33.5 MB)
  const bool mfma_ok = (ws_size >= 134742016ull);

  if (mfma_ok) {
    // layer 0: x->fp16, pack Wih0, MFMA GEMM (K=256)
    conv16<<<dim3((MROWS * FF / 8 + 255) / 256), 256, 0, stream>>>(x, xh, MROWS * FF / 8);
    pack_wih<<<dim3(192), 256, 0, stream>>>(Wih0, pWih, FF);
    gemm_mfma<<<dim3(12, 128), 256, 0, stream>>>(xh, pWih, bih0, gibuf, FF);

    // layer 0 scan
    pack_whh<<<dim3(384), 256, 0, stream>>>(Whh0, pWhh);
    hipMemsetAsync(flags, 0, SGRP * NGRP * TT * sizeof(unsigned int), stream);
    gru_scan_mfma<<<dim3(SGRP * NGRP), 512, 0, stream>>>(gibuf, pWhh, bhh0, hfin, y0h, hx, flags);

    // layer 1: pack Wih1, MFMA GEMM (K=512) on fp16 y0
    pack_wih<<<dim3(384), 256, 0, stream>>>(Wih1, pWih, HH);
    gemm_mfma<<<dim3(12, 128), 256, 0, stream>>>(y0h, pWih, bih1, gibuf, HH);

    // layer 1 scan
    pack_whh<<<dim3(384), 256, 0, stream>>>(Whh1, pWhh);
    hipMemsetAsync(flags, 0, SGRP * NGRP * TT * sizeof(unsigned int), stream);
    gru_scan_mfma<<<dim3(SGRP * NGRP), 512, 0, stream>>>(gibuf, pWhh, bhh1, hfin, nullptr, hx, flags);
  } else {
    gemm_bias<<<dim3(G3 / TNg, MROWS / TMg), 256, 0, stream>>>(x, Wih0, bih0, gibuf, MROWS, G3, FF);
    gru_scan2f<<<dim3(NSEQ / QS), SCTH, 0, stream>>>(gibuf, Whh0, bhh0, hfin, y0f);
    gemm_bias<<<dim3(G3 / TNg, MROWS / TMg), 256, 0, stream>>>(y0f, Wih1, bih1, gibuf, MROWS, G3, HH);
    gru_scan2f<<<dim3(NSEQ / QS), SCTH, 0, stream>>>(gibuf, Whh1, bhh1, hfin, nullptr);
  }

  fc_mean<<<dim3(BB), 256, 0, stream>>>(hfin, fcW, fcb, out);
}

// Round 21
// 617.951 us; speedup vs baseline: 6.0862x; 1.0012x over previous
//
#include <hip/hip_runtime.h>
#include <math.h>

// Problem dims (fixed by reference)
#define BB 32
#define CC 8
#define TT 64
#define FF 256
#define HH 512
#define G3 1536
#define NSEQ 256            // BB*CC
#define MROWS 16384         // NSEQ*TT

#define SGRP 16             // sequence groups (16 seqs each)
#define NGRP 4              // N-split ways (384 preact cols each)

typedef _Float16 f16x8 __attribute__((ext_vector_type(8)));
typedef float f32x4 __attribute__((ext_vector_type(4)));

// ---------------- fallback fp32 input GEMM ----------------
#define TMg 128
#define TNg 128
#define TKg 16

__global__ __launch_bounds__(256) void gemm_bias(
    const float* __restrict__ A, const float* __restrict__ W,
    const float* __restrict__ bias, float* __restrict__ C,
    int M, int N, int K)
{
  __shared__ float As[TKg][TMg + 4];
  __shared__ float Ws[TKg][TNg + 4];
  const int bm = blockIdx.y * TMg;
  const int bn = blockIdx.x * TNg;
  const int tid = threadIdx.x;
  const int tx = tid & 15;
  const int ty = tid >> 4;
  float acc[8][8];
#pragma unroll
  for (int i = 0; i < 8; ++i)
#pragma unroll
    for (int j = 0; j < 8; ++j) acc[i][j] = 0.f;

  for (int k0 = 0; k0 < K; k0 += TKg) {
    __syncthreads();
#pragma unroll
    for (int i = 0; i < 8; ++i) {
      int e = i * 256 + tid;
      int r = e >> 4;
      int c = e & 15;
      As[c][r] = A[(size_t)(bm + r) * K + (k0 + c)];
      Ws[c][r] = W[(size_t)(bn + r) * K + (k0 + c)];
    }
    __syncthreads();
#pragma unroll
    for (int k = 0; k < TKg; ++k) {
      float a[8], w[8];
#pragma unroll
      for (int i = 0; i < 8; ++i) a[i] = As[k][ty * 8 + i];
#pragma unroll
      for (int j = 0; j < 8; ++j) w[j] = Ws[k][tx + 16 * j];
#pragma unroll
      for (int i = 0; i < 8; ++i)
#pragma unroll
        for (int j = 0; j < 8; ++j) acc[i][j] = fmaf(a[i], w[j], acc[i][j]);
    }
  }
#pragma unroll
  for (int i = 0; i < 8; ++i) {
    size_t m = (size_t)(bm + ty * 8 + i);
#pragma unroll
    for (int j = 0; j < 8; ++j) {
      int n = bn + tx + 16 * j;
      C[m * N + n] = acc[i][j] + bias[n];
    }
  }
}

// ---------------- fp32 -> fp16 convert (vectorized x8) ----------------
__global__ __launch_bounds__(256) void conv16(
    const float* __restrict__ x, _Float16* __restrict__ xh, int n8)
{
  int i = blockIdx.x * 256 + threadIdx.x;
  if (i < n8) {
    float4 a = reinterpret_cast<const float4*>(x)[i * 2];
    float4 b = reinterpret_cast<const float4*>(x)[i * 2 + 1];
    f16x8 v;
    v[0] = (_Float16)a.x; v[1] = (_Float16)a.y; v[2] = (_Float16)a.z; v[3] = (_Float16)a.w;
    v[4] = (_Float16)b.x; v[5] = (_Float16)b.y; v[6] = (_Float16)b.z; v[7] = (_Float16)b.w;
    reinterpret_cast<f16x8*>(xh)[i] = v;
  }
}

// ---------------- pack W[G3][K] fp32 -> fp16 B-fragments ----------------
// P[tile(96)][kc(K/32)][lane(64)][8]; B-frag: n=lane&15 (W row in tile), k=kc*32+(lane>>4)*8+i
__global__ __launch_bounds__(256) void pack_wih(
    const float* __restrict__ W, _Float16* __restrict__ P, int K)
{
  int id = blockIdx.x * 256 + threadIdx.x;
  int lane = id & 63;
  int kcs = K >> 5;
  int t6 = id >> 6;
  int kc = t6 % kcs;
  int tile = t6 / kcs;
  if (tile >= 96) return;
  int row = tile * 16 + (lane & 15);
  int k0 = kc * 32 + ((lane >> 4) * 8);
  const float* src = W + (size_t)row * K + k0;
  f16x8 v;
#pragma unroll
  for (int i = 0; i < 8; ++i) v[i] = (_Float16)src[i];
  *reinterpret_cast<f16x8*>(P + (size_t)id * 8) = v;
}

// ---------------- pack Whh[G3][HH] -> fp16 B-fragments, 4-way N-split order ------
// P[ng(4)][tl(24)][kc(16)][lane(64)][8]; tl = gate*8 + sub; global tile = gate*32+ng*8+sub
__global__ __launch_bounds__(256) void pack_whh(
    const float* __restrict__ W, _Float16* __restrict__ P)
{
  int id = blockIdx.x * 256 + threadIdx.x;    // 0 .. 98303
  int lane = id & 63;
  int kc = (id >> 6) & 15;
  int tidx = id >> 10;                        // 0..95 = ng*24 + tl
  int ng = tidx / 24;
  int tl = tidx % 24;
  int g = tl >> 3, sub = tl & 7;
  int gt = g * 32 + ng * 8 + sub;
  int row = gt * 16 + (lane & 15);
  int k0 = kc * 32 + ((lane >> 4) * 8);
  const float* src = W + (size_t)row * HH + k0;
  f16x8 v;
#pragma unroll
  for (int i = 0; i < 8; ++i) v[i] = (_Float16)src[i];
  *reinterpret_cast<f16x8*>(P + (size_t)id * 8) = v;
}

// ---------------- MFMA input GEMM (r14-proven): C = A(fp16) @ Wpack^T + bias ----------
__device__ __forceinline__ void gload16g(const _Float16* g, _Float16* l) {
  __builtin_amdgcn_global_load_lds(
      (const __attribute__((address_space(1))) unsigned int*)g,
      (__attribute__((address_space(3))) unsigned int*)l, 16, 0, 0);
}

__global__ __launch_bounds__(256, 2) void gemm_mfma(
    const _Float16* __restrict__ A,   // [MROWS][K] fp16
    const _Float16* __restrict__ Bp,  // packed [96][K/32][64][8]
    const float* __restrict__ bias,   // [G3]
    float* __restrict__ C,            // [MROWS][G3]
    int K)
{
  __shared__ __align__(16) _Float16 As[2][128][36];   // 18.4 KB padded
  __shared__ __align__(16) _Float16 Bs[2][8 * 512];   // 16 KB (frag order)

  const int tid = threadIdx.x;
  const int lane = tid & 63;
  const int wv = tid >> 6;
  const int wm = wv >> 1, wn = wv & 1;
  const int bnT = blockIdx.x * 8;             // first of 8 n-tiles
  const int bm = blockIdx.y * 128;
  const int kcs = K >> 5;

  const int arow = lane & 15;
  const int agrp = lane >> 4;
  const int dcol = lane & 15;
  const int mrow = (lane >> 4) * 4;

  f32x4 acc[4][4];
#pragma unroll
  for (int i = 0; i < 4; ++i)
#pragma unroll
    for (int j = 0; j < 4; ++j) acc[i][j] = (f32x4){0.f, 0.f, 0.f, 0.f};

  auto stageA = [&](int s, int b) {
#pragma unroll
    for (int p = 0; p < 2; ++p) {
      int idx = p * 256 + tid;
      int row = idx >> 2;
      int cs = idx & 3;
      f16x8 v = *reinterpret_cast<const f16x8*>(
          A + (size_t)(bm + row) * K + s * 32 + cs * 8);
      *reinterpret_cast<f16x8*>(&As[b][row][cs * 8]) = v;
    }
  };
  auto stageB = [&](int s, int b) {
#pragma unroll
    for (int q = 0; q < 2; ++q) {
      int nt = wv * 2 + q;
      const _Float16* src = Bp + ((size_t)((bnT + nt) * kcs + s) * 64 + lane) * 8;
      gload16g(src, &Bs[b][nt * 512]);
    }
  };

  stageA(0, 0);
  stageB(0, 0);
  __syncthreads();

  for (int s = 0; s < kcs; ++s) {
    const int b = s & 1;
    if (s + 1 < kcs) {
      stageA(s + 1, b ^ 1);
      stageB(s + 1, b ^ 1);
    }
    f16x8 af[4], bf[4];
#pragma unroll
    for (int mt = 0; mt < 4; ++mt)
      af[mt] = *reinterpret_cast<const f16x8*>(&As[b][wm * 64 + mt * 16 + arow][agrp * 8]);
#pragma unroll
    for (int nt = 0; nt < 4; ++nt)
      bf[nt] = *reinterpret_cast<const f16x8*>(&Bs[b][(wn * 4 + nt) * 512 + lane * 8]);
#pragma unroll
    for (int mt = 0; mt < 4; ++mt)
#pragma unroll
      for (int nt = 0; nt < 4; ++nt)
        acc[mt][nt] = __builtin_amdgcn_mfma_f32_16x16x32_f16(af[mt], bf[nt], acc[mt][nt], 0, 0, 0);
    __syncthreads();
  }

  // ---- epilogue: bias + store ----
#pragma unroll
  for (int nt = 0; nt < 4; ++nt) {
    const int n = (bnT + wn * 4 + nt) * 16 + dcol;
    const float bv = bias[n];
#pragma unroll
    for (int mt = 0; mt < 4; ++mt) {
      const size_t m0 = (size_t)(bm + wm * 64 + mt * 16 + mrow);
#pragma unroll
      for (int r = 0; r < 4; ++r)
        C[(m0 + r) * G3 + n] = acc[mt][nt][r] + bv;
    }
  }
}

// ---------------- MFMA recurrent scan: fenceless sc0/sc1 + PINNED register weights ----
// r18/r19-proven fenceless protocol (sc0/sc1 LLC-bypass hx, relaxed flags, no
// invalidates). NEW vs r19: the 3 weight tiles (192 VGPR) are pinned live via an
// empty inline-asm "+v" on every fragment — asm-defined values cannot be
// rematerialized/sunk by the allocator (the r19 `VGPR=128` showed plain hoisting
// is defeated). This removes the per-step 384 KB warm-L2 weight re-read (~2.5 us
// of the 4.2 us/step). 8-wave block => 2 waves/SIMD => 256-VGPR HW cap; budget
// ~250. If the allocator spills instead, scratch traffic will show as regression.
#define SPB2 16
#define HSTR 520

#define LOADW(buf, g)                                                            \
  {                                                                              \
    const _Float16* _s = packW +                                                 \
        (((size_t)(ng * 24 + (g) * 8 + wid)) * 16) * 512 + (size_t)lane * 8;     \
    _Pragma("unroll")                                                            \
    for (int kc = 0; kc < 16; ++kc)                                              \
      buf[kc] = *reinterpret_cast<const f16x8*>(_s + (size_t)kc * 512);          \
  }

#define MF16(buf, acc)                                                           \
  {                                                                              \
    _Pragma("unroll")                                                            \
    for (int kc = 0; kc < 16; ++kc) {                                            \
      f16x8 _ha = *reinterpret_cast<const f16x8*>(&hs[arow][kc * 32 + agrp * 8]); \
      acc = __builtin_amdgcn_mfma_f32_16x16x32_f16(_ha, buf[kc], acc, 0, 0, 0);  \
    }                                                                            \
  }

__global__ __launch_bounds__(512, 1) void gru_scan_mfma(
    const float* __restrict__ gi,      // [NSEQ][TT][G3]
    const _Float16* __restrict__ packW,
    const float* __restrict__ bhh,     // [G3]
    float* __restrict__ hfin,          // [NSEQ][HH]
    _Float16* __restrict__ yout,       // [NSEQ][TT][HH] fp16 or nullptr
    _Float16* __restrict__ hx,         // [2][NSEQ][HH] exchange (LLC-only via sc0/sc1)
    unsigned int* __restrict__ flags)  // [SGRP][NGRP][TT], zeroed pre-launch
{
  __shared__ __align__(16) _Float16 hs[SPB2][HSTR];   // 16.6 KB

  const int tid = threadIdx.x;
  const int lane = tid & 63;
  const int wid = tid >> 6;                   // 0..7
  const int bid = blockIdx.x;
  const int sg = bid >> 2;                    // seq group
  const int ng = bid & 3;                     // N group (uniform per XCD: 8 % 4 == 0)
  const int seq0 = sg * SPB2;

  const int arow = lane & 15;
  const int agrp = lane >> 4;
  const int dcol = lane & 15;
  const int mrow = (lane >> 4) * 4;

  const int cg = ng * 128 + wid * 16 + dcol;

  const float bhr = bhh[cg];
  const float bhz = bhh[HH + cg];
  const float bhn = bhh[2 * HH + cg];

  // ---- persistent weight fragments: loaded ONCE, pinned live via inline asm ----
  f16x8 wbR[16], wbZ[16], wbN[16];
  LOADW(wbR, 0)
  LOADW(wbZ, 1)
  LOADW(wbN, 2)
#pragma unroll
  for (int kc = 0; kc < 16; ++kc)
    asm volatile("" : "+v"(wbR[kc]), "+v"(wbZ[kc]), "+v"(wbN[kc]));

  float hold[4] = {0.f, 0.f, 0.f, 0.f};

  for (int e = tid; e < SPB2 * HSTR; e += 512)
    hs[e / HSTR][e % HSTR] = (_Float16)0.f;
  __syncthreads();

  for (int t = 0; t < TT; ++t) {
    // ---- gi loads: prev-kernel data, independent of hx -> issue BEFORE the poll ----
    float gir[4], giz[4], gin[4];
#pragma unroll
    for (int r = 0; r < 4; ++r) {
      const float* p0 = gi + ((size_t)(seq0 + mrow + r) * TT + t) * G3;
      gir[r] = p0[cg];
      giz[r] = p0[HH + cg];
      gin[r] = p0[2 * HH + cg];
    }

    if (t > 0) {
      // 4 relaxed poller lanes, one per producer (separate flag rows; no invalidates)
      if (tid < NGRP) {
        const unsigned int* fp = &flags[((size_t)sg * NGRP + tid) * TT + (t - 1)];
        while (__hip_atomic_load(fp, __ATOMIC_RELAXED, __HIP_MEMORY_SCOPE_AGENT) == 0u) {}
      }
      __syncthreads();
      // copy h(t-1) from hx[t&1] via sc0/sc1 BYPASS loads (LLC-direct, cache-proof)
      {
        const _Float16* src = hx + (size_t)(t & 1) * NSEQ * HH
                              + (size_t)seq0 * HH + (size_t)tid * 16;
        f16x8 v0, v1;
        asm volatile(
            "global_load_dwordx4 %0, %2, off sc0 sc1\n\t"
            "global_load_dwordx4 %1, %2, off offset:16 sc0 sc1\n\t"
            "s_waitcnt vmcnt(0)"
            : "=&v"(v0), "=&v"(v1) : "v"(src) : "memory");
        int e0 = tid * 16;
        int row = e0 >> 9;
        int col = e0 & 511;
        *reinterpret_cast<f16x8*>(&hs[row][col]) = v0;
        *reinterpret_cast<f16x8*>(&hs[row][col + 8]) = v1;
      }
      __syncthreads();
    }

    f32x4 aR = {0.f,0.f,0.f,0.f}, aZ = {0.f,0.f,0.f,0.f}, aN = {0.f,0.f,0.f,0.f};
    MF16(wbR, aR)
    MF16(wbZ, aZ)
    MF16(wbN, aN)

    const int nb = (t + 1) & 1;
#pragma unroll
    for (int r = 0; r < 4; ++r) {
      float hr = aR[r] + bhr;
      float hz = aZ[r] + bhz;
      float hn = aN[r] + bhn;
      float rr = __builtin_amdgcn_rcpf(1.f + __expf(-(gir[r] + hr)));
      float zz = __builtin_amdgcn_rcpf(1.f + __expf(-(giz[r] + hz)));
      float ex = __expf(2.f * (gin[r] + rr * hn));
      float nn = 1.f - 2.f * __builtin_amdgcn_rcpf(ex + 1.f);
      float hnew = nn + zz * (hold[r] - nn);
      hold[r] = hnew;
      // hx store: sc0/sc1 write-through to LLC (no dirty L2)
      {
        _Float16 h16 = (_Float16)hnew;
        unsigned int hv32 = (unsigned int)__builtin_bit_cast(unsigned short, h16);
        _Float16* addr = hx + (size_t)nb * NSEQ * HH
                         + (size_t)(seq0 + mrow + r) * HH + cg;
        asm volatile("global_store_short %0, %1, off sc0 sc1"
                     :: "v"(addr), "v"(hv32) : "memory");
      }
      if (yout)
        yout[((size_t)(seq0 + mrow + r) * TT + t) * HH + cg] = (_Float16)hnew;
    }

    // publish: drain stores to LLC, barrier, relaxed flag store
    asm volatile("s_waitcnt vmcnt(0)" ::: "memory");
    __syncthreads();
    if (tid == 0)
      __hip_atomic_store(&flags[((size_t)sg * NGRP + ng) * TT + t], 1u,
                         __ATOMIC_RELAXED, __HIP_MEMORY_SCOPE_AGENT);
  }

#pragma unroll
  for (int r = 0; r < 4; ++r)
    hfin[(size_t)(seq0 + mrow + r) * HH + cg] = hold[r];
}

// ---------------- fallback fp32 scan (row-streaming) ----------------
#define QS 4
#define SCTH 512
__global__ __launch_bounds__(SCTH) void gru_scan2f(
    const float* __restrict__ gi, const float* __restrict__ W,
    const float* __restrict__ bhh, float* __restrict__ hfin,
    float* __restrict__ yout)
{
  __shared__ __align__(16) float hsl[HH][QS];
  const int col = threadIdx.x;
  const int seq0 = blockIdx.x * QS;
  const float bh0 = bhh[col];
  const float bh1 = bhh[HH + col];
  const float bh2 = bhh[2 * HH + col];
  const float* w0p = W + (size_t)col * HH;
  const float* w1p = W + (size_t)(HH + col) * HH;
  const float* w2p = W + (size_t)(2 * HH + col) * HH;

  *reinterpret_cast<float4*>(&hsl[col][0]) = make_float4(0.f, 0.f, 0.f, 0.f);
  __syncthreads();

  for (int t = 0; t < TT; ++t) {
    float acc0[QS], acc1[QS], acc2[QS];
#pragma unroll
    for (int s = 0; s < QS; ++s) { acc0[s] = bh0; acc1[s] = bh1; acc2[s] = bh2; }
    float4 ho = *reinterpret_cast<const float4*>(&hsl[col][0]);
    float hold[QS] = {ho.x, ho.y, ho.z, ho.w};
#pragma unroll 2
    for (int k0 = 0; k0 < HH; k0 += 4) {
      float w[3][4];
      float4 a = *reinterpret_cast<const float4*>(&w0p[k0]);
      w[0][0] = a.x; w[0][1] = a.y; w[0][2] = a.z; w[0][3] = a.w;
      float4 b = *reinterpret_cast<const float4*>(&w1p[k0]);
      w[1][0] = b.x; w[1][1] = b.y; w[1][2] = b.z; w[1][3] = b.w;
      float4 c = *reinterpret_cast<const float4*>(&w2p[k0]);
      w[2][0] = c.x; w[2][1] = c.y; w[2][2] = c.z; w[2][3] = c.w;
#pragma unroll
      for (int kk = 0; kk < 4; ++kk) {
        float4 h4 = *reinterpret_cast<const float4*>(&hsl[k0 + kk][0]);
        float hq[4] = {h4.x, h4.y, h4.z, h4.w};
#pragma unroll
        for (int s = 0; s < QS; ++s) {
          acc0[s] = fmaf(hq[s], w[0][kk], acc0[s]);
          acc1[s] = fmaf(hq[s], w[1][kk], acc1[s]);
          acc2[s] = fmaf(hq[s], w[2][kk], acc2[s]);
        }
      }
    }
    __syncthreads();
    float hnew[QS];
#pragma unroll
    for (int s = 0; s < QS; ++s) {
      size_t grow = ((size_t)(seq0 + s) * TT + t) * G3;
      float ir = gi[grow + col];
      float iz = gi[grow + HH + col];
      float inn = gi[grow + 2 * HH + col];
      float r = 1.f / (1.f + expf(-(ir + acc0[s])));
      float z = 1.f / (1.f + expf(-(iz + acc1[s])));
      float nn = tanhf(inn + r * acc2[s]);
      hnew[s] = (1.f - z) * nn + z * hold[s];
      if (yout) yout[((size_t)(seq0 + s) * TT + t) * HH + col] = hnew[s];
    }
    *reinterpret_cast<float4*>(&hsl[col][0]) =
        make_float4(hnew[0], hnew[1], hnew[2], hnew[3]);
    __syncthreads();
  }
#pragma unroll
  for (int s = 0; s < QS; ++s)
    hfin[(size_t)(seq0 + s) * HH + col] = hsl[col][s];
}

// ---------------- final FC + channel mean ----------------
__global__ __launch_bounds__(256) void fc_mean(
    const float* __restrict__ hfin, const float* __restrict__ fcW,
    const float* __restrict__ fcb, float* __restrict__ out)
{
  __shared__ float red[256];
  const int b = blockIdx.x;
  const int tid = threadIdx.x;
  float sum = 0.f;
  for (int e = tid; e < CC * HH; e += 256) {
    int c = e >> 9;
    int k = e & (HH - 1);
    sum += hfin[(size_t)(b * CC + c) * HH + k] * fcW[k];
  }
  red[tid] = sum;
  __syncthreads();
  for (int w = 128; w > 0; w >>= 1) {
    if (tid < w) red[tid] += red[tid + w];
    __syncthreads();
  }
  if (tid == 0) out[b] = red[0] * (1.f / CC) + fcb[0];
}

extern "C" void kernel_launch(void* const* d_in, const int* in_sizes, int n_in,
                              void* d_out, int out_size, void* d_ws, size_t ws_size,
                              hipStream_t stream)
{
  const float* x    = (const float*)d_in[0];
  const float* Wih0 = (const float*)d_in[1];
  const float* Whh0 = (const float*)d_in[2];
  const float* bih0 = (const float*)d_in[3];
  const float* bhh0 = (const float*)d_in[4];
  const float* Wih1 = (const float*)d_in[5];
  const float* Whh1 = (const float*)d_in[6];
  const float* bih1 = (const float*)d_in[7];
  const float* bhh1 = (const float*)d_in[8];
  const float* fcW  = (const float*)d_in[9];
  const float* fcb  = (const float*)d_in[10];
  float* out = (float*)d_out;

  // ws layout (fast path):
  //   gi    [MROWS][G3] fp32  100,663,296 @ 0
  //   y0h   [MROWS][HH] fp16   16,777,216 @ 100,663,296
  //   xh    [MROWS][FF] fp16    8,388,608 @ 117,440,512
  //   pWih  fp16 (K<=512)       1,572,864 @ 125,829,120
  //   pWhh  fp16                1,572,864 @ 127,401,984
  //   hx    [2][NSEQ][HH] fp16    524,288 @ 128,974,848
  //   flags [SGRP][NGRP][TT]       16,384 @ 129,499,136
  //   hfin  [NSEQ][HH] fp32       524,288 @ 134,217,728  (shared w/ fallback layout)
  char* ws = (char*)d_ws;
  float* gibuf = (float*)ws;
  _Float16* y0h  = (_Float16*)(ws + 100663296ull);
  _Float16* xh   = (_Float16*)(ws + 117440512ull);
  _Float16* pWih = (_Float16*)(ws + 125829120ull);
  _Float16* pWhh = (_Float16*)(ws + 127401984ull);
  _Float16* hx   = (_Float16*)(ws + 128974848ull);
  unsigned int* flags = (unsigned int*)(ws + 129499136ull);
  float* hfin = (float*)(ws + 134217728ull);
  float* y0f  = (float*)(ws + 100663296ull);   // fallback fp32 y0 (33.5 MB)
  const bool mfma_ok = (ws_size >= 134742016ull);

  if (mfma_ok) {
    // layer 0: x->fp16, pack Wih0, MFMA GEMM (K=256)
    conv16<<<dim3((MROWS * FF / 8 + 255) / 256), 256, 0, stream>>>(x, xh, MROWS * FF / 8);
    pack_wih<<<dim3(192), 256, 0, stream>>>(Wih0, pWih, FF);
    gemm_mfma<<<dim3(12, 128), 256, 0, stream>>>(xh, pWih, bih0, gibuf, FF);

    // layer 0 scan
    pack_whh<<<dim3(384), 256, 0, stream>>>(Whh0, pWhh);
    hipMemsetAsync(flags, 0, SGRP * NGRP * TT * sizeof(unsigned int), stream);
    gru_scan_mfma<<<dim3(SGRP * NGRP), 512, 0, stream>>>(gibuf, pWhh, bhh0, hfin, y0h, hx, flags);

    // layer 1: pack Wih1, MFMA GEMM (K=512) on fp16 y0
    pack_wih<<<dim3(384), 256, 0, stream>>>(Wih1, pWih, HH);
    gemm_mfma<<<dim3(12, 128), 256, 0, stream>>>(y0h, pWih, bih1, gibuf, HH);

    // layer 1 scan
    pack_whh<<<dim3(384), 256, 0, stream>>>(Whh1, pWhh);
    hipMemsetAsync(flags, 0, SGRP * NGRP * TT * sizeof(unsigned int), stream);
    gru_scan_mfma<<<dim3(SGRP * NGRP), 512, 0, stream>>>(gibuf, pWhh, bhh1, hfin, nullptr, hx, flags);
  } else {
    gemm_bias<<<dim3(G3 / TNg, MROWS / TMg), 256, 0, stream>>>(x, Wih0, bih0, gibuf, MROWS, G3, FF);
    gru_scan2f<<<dim3(NSEQ / QS), SCTH, 0, stream>>>(gibuf, Whh0, bhh0, hfin, y0f);
    gemm_bias<<<dim3(G3 / TNg, MROWS / TMg), 256, 0, stream>>>(y0f, Wih1, bih1, gibuf, MROWS, G3, HH);
    gru_scan2f<<<dim3(NSEQ / QS), SCTH, 0, stream>>>(gibuf, Whh1, bhh1, hfin, nullptr);
  }

  fc_mean<<<dim3(BB), 256, 0, stream>>>(hfin, fcW, fcb, out);
}